// Round 1
// baseline (2436.457 us; speedup 1.0000x reference)
//
#include <hip/hip_runtime.h>

#define NPIX 262144  // 512*512

// ---------------- reduction helper ----------------
__device__ inline float block_sum(float v, float* sm) {
  #pragma unroll
  for (int off = 32; off > 0; off >>= 1) v += __shfl_down(v, off, 64);
  int lane = threadIdx.x & 63, wid = threadIdx.x >> 6;
  __syncthreads();
  if (lane == 0) sm[wid] = v;
  __syncthreads();
  float r = 0.f;
  if (threadIdx.x < 4) r = sm[threadIdx.x];
  r += __shfl_down(r, 2, 64);
  r += __shfl_down(r, 1, 64);
  return r;  // thread 0 holds the block total
}

// ---------------- noise_pred: 320->4 3x3 conv, pad 1, 64x64 ----------------
__global__ __launch_bounds__(256) void k_init_noise(const float* __restrict__ bias,
                                                    float* __restrict__ out) {
  int i = blockIdx.x * 256 + threadIdx.x;  // 65536
  int c = (i >> 12) & 3;
  out[i] = bias[c];
}

__global__ __launch_bounds__(256) void k_conv_noise(const float* __restrict__ feat,
                                                    const float* __restrict__ w,
                                                    float* __restrict__ out) {
  // grid (16 tiles, B=4, 5 channel-chunks), block 256 (16x16)
  __shared__ float tile[324];
  __shared__ float wl[36];
  int b = blockIdx.y, c0 = blockIdx.z * 64;
  int tx = threadIdx.x & 15, ty = threadIdx.x >> 4;
  int tx0 = (blockIdx.x & 3) << 4, ty0 = (blockIdx.x >> 2) << 4;
  float acc[4] = {0.f, 0.f, 0.f, 0.f};
  for (int c = c0; c < c0 + 64; ++c) {
    for (int i = threadIdx.x; i < 324; i += 256) {
      int r = i / 18, cc = i % 18;
      int gy = ty0 + r - 1, gx = tx0 + cc - 1;
      float v = 0.f;
      if (gy >= 0 && gy < 64 && gx >= 0 && gx < 64)
        v = feat[((b * 320 + c) * 64 + gy) * 64 + gx];
      tile[i] = v;
    }
    if (threadIdx.x < 36)
      wl[threadIdx.x] = w[(threadIdx.x / 9) * 2880 + c * 9 + threadIdx.x % 9];
    __syncthreads();
    #pragma unroll
    for (int kh = 0; kh < 3; ++kh)
      #pragma unroll
      for (int kw = 0; kw < 3; ++kw) {
        float v = tile[(ty + kh) * 18 + tx + kw];
        #pragma unroll
        for (int o = 0; o < 4; ++o) acc[o] = fmaf(v, wl[o * 9 + kh * 3 + kw], acc[o]);
      }
    __syncthreads();
  }
  int y = ty0 + ty, x = tx0 + tx;
  #pragma unroll
  for (int o = 0; o < 4; ++o)
    atomicAdd(&out[((b * 4 + o) * 64 + y) * 64 + x], acc[o]);
}

// ---------------- r1: 1x1 conv 320->9 + ReLU ----------------
__global__ __launch_bounds__(256) void k_r1(const float* __restrict__ feat,
                                            const float* __restrict__ w,
                                            const float* __restrict__ bias,
                                            float* __restrict__ out) {
  __shared__ float wl[2880];
  __shared__ float bl[9];
  for (int i = threadIdx.x; i < 2880; i += 256) wl[i] = w[i];
  if (threadIdx.x < 9) bl[threadIdx.x] = bias[threadIdx.x];
  __syncthreads();
  int pix = blockIdx.x * 256 + threadIdx.x;  // 16384
  int b = pix >> 12, hw = pix & 4095;
  float acc[9] = {};
  const float* fp = feat + (size_t)(b * 320) * 4096 + hw;
  for (int c = 0; c < 320; ++c) {
    float v = fp[c * 4096];
    #pragma unroll
    for (int k = 0; k < 9; ++k) acc[k] = fmaf(v, wl[k * 320 + c], acc[k]);
  }
  float* op = out + (size_t)(b * 9) * 4096 + hw;
  #pragma unroll
  for (int k = 0; k < 9; ++k) op[k * 4096] = fmaxf(acc[k] + bl[k], 0.f);
}

// ---------------- 3x3 conv 9->9 + ReLU, pad 1 ----------------
__global__ __launch_bounds__(256) void k_conv9(const float* __restrict__ in,
                                               const float* __restrict__ w9,
                                               const float* __restrict__ bias,
                                               float* __restrict__ out, int H) {
  __shared__ float tile[9][324];
  __shared__ float wl[729];
  __shared__ float bl[9];
  int b = blockIdx.y;
  int tilesx = H >> 4;
  int tx0 = (blockIdx.x % tilesx) << 4, ty0 = (blockIdx.x / tilesx) << 4;
  int tx = threadIdx.x & 15, ty = threadIdx.x >> 4;
  for (int i = threadIdx.x; i < 729; i += 256) wl[i] = w9[i];
  if (threadIdx.x < 9) bl[threadIdx.x] = bias[threadIdx.x];
  for (int i = threadIdx.x; i < 9 * 324; i += 256) {
    int ci = i / 324, rem = i % 324;
    int r = rem / 18, cc = rem % 18;
    int gy = ty0 + r - 1, gx = tx0 + cc - 1;
    float v = 0.f;
    if (gy >= 0 && gy < H && gx >= 0 && gx < H)
      v = in[((size_t)(b * 9 + ci) * H + gy) * H + gx];
    tile[ci][rem] = v;
  }
  __syncthreads();
  float acc[9] = {};
  for (int ci = 0; ci < 9; ++ci) {
    #pragma unroll
    for (int kh = 0; kh < 3; ++kh)
      #pragma unroll
      for (int kw = 0; kw < 3; ++kw) {
        float v = tile[ci][(ty + kh) * 18 + tx + kw];
        #pragma unroll
        for (int k = 0; k < 9; ++k)
          acc[k] = fmaf(v, wl[(k * 9 + ci) * 9 + kh * 3 + kw], acc[k]);
      }
  }
  int y = ty0 + ty, x = tx0 + tx;
  #pragma unroll
  for (int k = 0; k < 9; ++k)
    out[((size_t)(b * 9 + k) * H + y) * H + x] = fmaxf(acc[k] + bl[k], 0.f);
}

// ---------------- transposed conv 9->9, k=4, s=2, p=1 ----------------
__global__ __launch_bounds__(256) void k_convt9(const float* __restrict__ in,
                                                const float* __restrict__ wt,
                                                const float* __restrict__ bias,
                                                float* __restrict__ out, int Hin) {
  __shared__ float tile[9][100];
  __shared__ float wl[1296];
  __shared__ float bl[9];
  int b = blockIdx.y;
  int Hout = Hin * 2;
  int tilesx = Hout >> 4;
  int tx0 = (blockIdx.x % tilesx) << 4, ty0 = (blockIdx.x / tilesx) << 4;
  int tx = threadIdx.x & 15, ty = threadIdx.x >> 4;
  int ihb = (ty0 >> 1) - 1, iwb = (tx0 >> 1) - 1;
  for (int i = threadIdx.x; i < 1296; i += 256) wl[i] = wt[i];
  if (threadIdx.x < 9) bl[threadIdx.x] = bias[threadIdx.x];
  for (int i = threadIdx.x; i < 900; i += 256) {
    int ci = i / 100, rem = i % 100;
    int r = rem / 10, cc = rem % 10;
    int gy = ihb + r, gx = iwb + cc;
    float v = 0.f;
    if (gy >= 0 && gy < Hin && gx >= 0 && gx < Hin)
      v = in[((size_t)(b * 9 + ci) * Hin + gy) * Hin + gx];
    tile[ci][rem] = v;
  }
  __syncthreads();
  int oy = ty0 + ty, ox = tx0 + tx;
  int p = oy & 1, q = ox & 1;
  int lr0 = ((oy + p - 2) >> 1) - ihb;
  int lc0 = ((ox + q - 2) >> 1) - iwb;
  float acc[9] = {};
  for (int ci = 0; ci < 9; ++ci) {
    #pragma unroll
    for (int a = 0; a < 2; ++a) {
      int kh = p + 2 * a, lr = lr0 + a;
      #pragma unroll
      for (int e = 0; e < 2; ++e) {
        int kw = q + 2 * e, lc = lc0 + e;
        float v = tile[ci][lr * 10 + lc];
        #pragma unroll
        for (int k = 0; k < 9; ++k)
          acc[k] = fmaf(v, wl[((ci * 9 + k) * 4 + (3 - kh)) * 4 + (3 - kw)], acc[k]);
      }
    }
  }
  #pragma unroll
  for (int k = 0; k < 9; ++k)
    out[((size_t)(b * 9 + k) * Hout + oy) * Hout + ox] = acc[k] + bl[k];
}

// ---------------- softmax over 9 channels + sum R^2 ----------------
__global__ __launch_bounds__(256) void k_softmax(const float* __restrict__ in,
                                                 float* __restrict__ R,
                                                 float* __restrict__ acc) {
  __shared__ float sm[4];
  int pix = blockIdx.x * 256 + threadIdx.x;  // 1048576
  int b = pix >> 18, hw = pix & (NPIX - 1);
  const float* ip = in + (size_t)(b * 9) * NPIX + hw;
  float v[9];
  float m = -1e30f;
  #pragma unroll
  for (int k = 0; k < 9; ++k) { v[k] = ip[(size_t)k * NPIX]; m = fmaxf(m, v[k]); }
  float s = 0.f;
  #pragma unroll
  for (int k = 0; k < 9; ++k) { v[k] = expf(v[k] - m); s += v[k]; }
  float inv = 1.f / s;
  float* rp = R + (size_t)(b * 9) * NPIX + hw;
  float sq = 0.f;
  #pragma unroll
  for (int k = 0; k < 9; ++k) {
    float r = v[k] * inv;
    rp[(size_t)k * NPIX] = r;
    sq += r * r;
  }
  float t = block_sum(sq, sm);
  if (threadIdx.x == 0) atomicAdd(acc + 0, t);
}

// ---------------- tv_R sums ----------------
__global__ __launch_bounds__(256) void k_tvr(const float* __restrict__ R,
                                             float* __restrict__ acc) {
  __shared__ float sm[4];
  size_t e = (size_t)blockIdx.x * 256 + threadIdx.x;  // 9437184
  int w = e & 511, h = (e >> 9) & 511;
  float v = R[e];
  float s1 = 0.f, s2 = 0.f;
  if (w < 511) s1 = fabsf(v - R[e + 1]);
  if (h < 511) s2 = fabsf(v - R[e + 512]);
  float t1 = block_sum(s1, sm);
  float t2 = block_sum(s2, sm);
  if (threadIdx.x == 0) { atomicAdd(acc + 1, t1); atomicAdd(acc + 2, t2); }
}

// ---------------- tri_sample + einsum ----------------
__global__ __launch_bounds__(256) void k_trisample(const float* __restrict__ img,
                                                   const float* __restrict__ luts,
                                                   const float* __restrict__ R,
                                                   float* __restrict__ outp) {
  int pix = blockIdx.x * 256 + threadIdx.x;  // 1048576
  int b = pix >> 18, hw = pix & (NPIX - 1);
  int i0[3], i1[3];
  float f[3];
  #pragma unroll
  for (int c = 0; c < 3; ++c) {
    float v = img[(size_t)(b * 3 + c) * NPIX + hw];
    float pos = (v * 0.5f + 0.5f) * 32.f;
    float fl = floorf(pos);
    int ii = (int)fl;
    ii = min(max(ii, 0), 32);
    i0[c] = ii;
    i1[c] = min(ii + 1, 32);
    f[c] = pos - fl;
  }
  float fr = f[0], fg = f[1], fb = f[2];
  int r0 = i0[0], g0 = i0[1], b0 = i0[2], r1 = i1[0], g1 = i1[1], b1 = i1[2];
  int off[8];
  off[0] = (b0 * 33 + g0) * 33 + r0;
  off[1] = (b0 * 33 + g0) * 33 + r1;
  off[2] = (b0 * 33 + g1) * 33 + r0;
  off[3] = (b0 * 33 + g1) * 33 + r1;
  off[4] = (b1 * 33 + g0) * 33 + r0;
  off[5] = (b1 * 33 + g0) * 33 + r1;
  off[6] = (b1 * 33 + g1) * 33 + r0;
  off[7] = (b1 * 33 + g1) * 33 + r1;
  float wt[8];
  wt[0] = (1 - fb) * (1 - fg) * (1 - fr);
  wt[1] = (1 - fb) * (1 - fg) * fr;
  wt[2] = (1 - fb) * fg * (1 - fr);
  wt[3] = (1 - fb) * fg * fr;
  wt[4] = fb * (1 - fg) * (1 - fr);
  wt[5] = fb * (1 - fg) * fr;
  wt[6] = fb * fg * (1 - fr);
  wt[7] = fb * fg * fr;
  float acc[3] = {0.f, 0.f, 0.f};
  for (int k = 0; k < 9; ++k) {
    float rk = R[(size_t)(b * 9 + k) * NPIX + hw];
    #pragma unroll
    for (int c = 0; c < 3; ++c) {
      const float* lp = luts + (size_t)(k * 3 + c) * 35937;
      float s = 0.f;
      #pragma unroll
      for (int j = 0; j < 8; ++j) s = fmaf(lp[off[j]], wt[j], s);
      acc[c] = fmaf(rk, s, acc[c]);
    }
  }
  #pragma unroll
  for (int c = 0; c < 3; ++c) outp[(size_t)(b * 3 + c) * NPIX + hw] = acc[c];
}

// ---------------- f1: 3->64 3x3 + ReLU (one batch) ----------------
__global__ __launch_bounds__(256) void k_f1(const float* __restrict__ inp,
                                            const float* __restrict__ w,
                                            const float* __restrict__ bias,
                                            float* __restrict__ h, int b) {
  __shared__ float tile[3][324];
  __shared__ float wl[432];
  __shared__ float bl[16];
  int g = blockIdx.y;
  int tx0 = (blockIdx.x & 31) << 4, ty0 = (blockIdx.x >> 5) << 4;
  int tx = threadIdx.x & 15, ty = threadIdx.x >> 4;
  for (int i = threadIdx.x; i < 432; i += 256) wl[i] = w[g * 432 + i];
  if (threadIdx.x < 16) bl[threadIdx.x] = bias[g * 16 + threadIdx.x];
  for (int i = threadIdx.x; i < 3 * 324; i += 256) {
    int ci = i / 324, rem = i % 324;
    int r = rem / 18, cc = rem % 18;
    int gy = ty0 + r - 1, gx = tx0 + cc - 1;
    float v = 0.f;
    if (gy >= 0 && gy < 512 && gx >= 0 && gx < 512)
      v = inp[(size_t)(b * 3 + ci) * NPIX + gy * 512 + gx];
    tile[ci][rem] = v;
  }
  __syncthreads();
  float acc[16] = {};
  for (int ci = 0; ci < 3; ++ci)
    #pragma unroll
    for (int kh = 0; kh < 3; ++kh)
      #pragma unroll
      for (int kw = 0; kw < 3; ++kw) {
        float v = tile[ci][(ty + kh) * 18 + tx + kw];
        #pragma unroll
        for (int o = 0; o < 16; ++o)
          acc[o] = fmaf(v, wl[(o * 3 + ci) * 9 + kh * 3 + kw], acc[o]);
      }
  int y = ty0 + ty, x = tx0 + tx;
  #pragma unroll
  for (int o = 0; o < 16; ++o)
    h[(size_t)(g * 16 + o) * NPIX + y * 512 + x] = fmaxf(acc[o] + bl[o], 0.f);
}

// ---------------- f2: 64->3 3x3 (one batch) ----------------
__global__ __launch_bounds__(256) void k_f2(const float* __restrict__ h,
                                            const float* __restrict__ w,
                                            const float* __restrict__ bias,
                                            float* __restrict__ outp, int b) {
  __shared__ float tile[8][324];
  __shared__ float wl[1728];
  int tx0 = (blockIdx.x & 31) << 4, ty0 = (blockIdx.x >> 5) << 4;
  int tx = threadIdx.x & 15, ty = threadIdx.x >> 4;
  for (int i = threadIdx.x; i < 1728; i += 256) wl[i] = w[i];
  float acc[3] = {0.f, 0.f, 0.f};
  for (int c0 = 0; c0 < 64; c0 += 8) {
    __syncthreads();
    for (int i = threadIdx.x; i < 8 * 324; i += 256) {
      int ci = i / 324, rem = i % 324;
      int r = rem / 18, cc = rem % 18;
      int gy = ty0 + r - 1, gx = tx0 + cc - 1;
      float v = 0.f;
      if (gy >= 0 && gy < 512 && gx >= 0 && gx < 512)
        v = h[(size_t)(c0 + ci) * NPIX + gy * 512 + gx];
      tile[ci][rem] = v;
    }
    __syncthreads();
    for (int ci = 0; ci < 8; ++ci)
      #pragma unroll
      for (int kh = 0; kh < 3; ++kh)
        #pragma unroll
        for (int kw = 0; kw < 3; ++kw) {
          float v = tile[ci][(ty + kh) * 18 + tx + kw];
          #pragma unroll
          for (int o = 0; o < 3; ++o)
            acc[o] = fmaf(v, wl[(o * 64 + c0 + ci) * 9 + kh * 3 + kw], acc[o]);
        }
  }
  int y = ty0 + ty, x = tx0 + tx;
  #pragma unroll
  for (int o = 0; o < 3; ++o)
    outp[(size_t)(b * 3 + o) * NPIX + y * 512 + x] = acc[o] + bias[o];
}

// ---------------- tv3d + mono on luts ----------------
__global__ __launch_bounds__(256) void k_tv3d(const float* __restrict__ luts,
                                              float* __restrict__ acc) {
  __shared__ float sm[4];
  int e = blockIdx.x * 256 + threadIdx.x;
  float tv = 0.f, mn = 0.f;
  if (e < 970299) {
    int rem = e % 35937;
    int ib = rem / 1089, ig = (rem / 33) % 33, ir = rem % 33;
    float v = luts[e];
    if (ir < 32) {
      float d = v - luts[e + 1];
      float wgt = (ir == 0 || ir == 31) ? 2.f : 1.f;
      tv += wgt * d * d;
      mn += fmaxf(d, 0.f);
    }
    if (ig < 32) {
      float d = v - luts[e + 33];
      float wgt = (ig == 0 || ig == 31) ? 2.f : 1.f;
      tv += wgt * d * d;
      mn += fmaxf(d, 0.f);
    }
    if (ib < 32) {
      float d = v - luts[e + 1089];
      float wgt = (ib == 0 || ib == 31) ? 2.f : 1.f;
      tv += wgt * d * d;
      mn += fmaxf(d, 0.f);
    }
  }
  float t1 = block_sum(tv, sm);
  float t2 = block_sum(mn, sm);
  if (threadIdx.x == 0) { atomicAdd(acc + 3, t1); atomicAdd(acc + 4, t2); }
}

// ---------------- finalize scalar ----------------
__global__ void k_final(const float* __restrict__ acc, float* __restrict__ out) {
  float weights_norm = acc[0] / 9437184.f;
  float tvR = acc[1] / 9418752.f + acc[2] / 9418752.f;
  float tvc = acc[3] / 104544.f;
  float mnc = acc[4] / 104544.f;
  out[0] = 0.001f * (weights_norm + tvc + tvR) + 10.f * mnc;
}

extern "C" void kernel_launch(void* const* d_in, const int* in_sizes, int n_in,
                              void* d_out, int out_size, void* d_ws, size_t ws_size,
                              hipStream_t stream) {
  const float* feat = (const float*)d_in[0];
  const float* img = (const float*)d_in[1];
  const float* conv_out_w = (const float*)d_in[2];
  const float* conv_out_b = (const float*)d_in[3];
  const float* r1_w = (const float*)d_in[4];
  const float* r1_b = (const float*)d_in[5];
  const float* r2_w = (const float*)d_in[6];
  const float* r2_b = (const float*)d_in[7];
  const float* rt1_w = (const float*)d_in[8];
  const float* rt1_b = (const float*)d_in[9];
  const float* r3_w = (const float*)d_in[10];
  const float* r3_b = (const float*)d_in[11];
  const float* rt2_w = (const float*)d_in[12];
  const float* rt2_b = (const float*)d_in[13];
  const float* r4_w = (const float*)d_in[14];
  const float* r4_b = (const float*)d_in[15];
  const float* rt3_w = (const float*)d_in[16];
  const float* rt3_b = (const float*)d_in[17];
  const float* luts = (const float*)d_in[18];
  const float* f1_w = (const float*)d_in[19];
  const float* f1_b = (const float*)d_in[20];
  const float* f2_w = (const float*)d_in[21];
  const float* f2_b = (const float*)d_in[22];

  float* out_noise = (float*)d_out;       // 65536
  float* out_img = out_noise + 65536;     // 3145728
  float* out_loss = out_img + 3145728;    // 1

  char* ws = (char*)d_ws;
  float* acc = (float*)ws;                                 // 16 floats
  float* bufA = (float*)(ws + 256);                        // 37748736 B
  float* bufB = (float*)(ws + 256 + 37748736);             // 37748736 B
  float* lutp = (float*)(ws + 256 + 2ll * 37748736);       // 12582912 B
  float* hbuf = bufA;  // 64*512*512*4 = 67MB, reuses A+part of B (R dead by then)

  hipMemsetAsync(acc, 0, 64, stream);

  k_init_noise<<<256, 256, 0, stream>>>(conv_out_b, out_noise);
  k_conv_noise<<<dim3(16, 4, 5), 256, 0, stream>>>(feat, conv_out_w, out_noise);
  k_r1<<<64, 256, 0, stream>>>(feat, r1_w, r1_b, bufA);
  k_conv9<<<dim3(16, 4), 256, 0, stream>>>(bufA, r2_w, r2_b, bufB, 64);
  k_convt9<<<dim3(64, 4), 256, 0, stream>>>(bufB, rt1_w, rt1_b, bufA, 64);
  k_conv9<<<dim3(64, 4), 256, 0, stream>>>(bufA, r3_w, r3_b, bufB, 128);
  k_convt9<<<dim3(256, 4), 256, 0, stream>>>(bufB, rt2_w, rt2_b, bufA, 128);
  k_conv9<<<dim3(256, 4), 256, 0, stream>>>(bufA, r4_w, r4_b, bufB, 256);
  k_convt9<<<dim3(1024, 4), 256, 0, stream>>>(bufB, rt3_w, rt3_b, bufA, 256);
  k_softmax<<<4096, 256, 0, stream>>>(bufA, bufB, acc);
  k_tvr<<<36864, 256, 0, stream>>>(bufB, acc);
  k_trisample<<<4096, 256, 0, stream>>>(img, luts, bufB, lutp);
  for (int b = 0; b < 4; ++b) {
    k_f1<<<dim3(1024, 4), 256, 0, stream>>>(lutp, f1_w, f1_b, hbuf, b);
    k_f2<<<1024, 256, 0, stream>>>(hbuf, f2_w, f2_b, out_img, b);
  }
  k_tv3d<<<3791, 256, 0, stream>>>(luts, acc);
  k_final<<<1, 1, 0, stream>>>(acc, out_loss);
}

// Round 2
// 1171.868 us; speedup vs baseline: 2.0791x; 2.0791x over previous
//
#include <hip/hip_runtime.h>

#define NPIX 262144  // 512*512

// ---------------- reduction helper ----------------
__device__ inline float block_sum(float v, float* sm) {
  #pragma unroll
  for (int off = 32; off > 0; off >>= 1) v += __shfl_down(v, off, 64);
  int lane = threadIdx.x & 63, wid = threadIdx.x >> 6;
  __syncthreads();
  if (lane == 0) sm[wid] = v;
  __syncthreads();
  float r = 0.f;
  if (threadIdx.x < 4) r = sm[threadIdx.x];
  r += __shfl_down(r, 2, 64);
  r += __shfl_down(r, 1, 64);
  return r;  // thread 0 holds the block total
}

// ---------------- noise_pred: 320->4 3x3 conv, pad 1, 64x64 ----------------
__global__ __launch_bounds__(256) void k_init_noise(const float* __restrict__ bias,
                                                    float* __restrict__ out) {
  int i = blockIdx.x * 256 + threadIdx.x;  // 65536
  int c = (i >> 12) & 3;
  out[i] = bias[c];
}

// 16-channel LDS staging per iteration; 20 channel chunks (z), atomics into out.
__global__ __launch_bounds__(256) void k_conv_noise(const float* __restrict__ feat,
                                                    const float* __restrict__ w,
                                                    float* __restrict__ out) {
  __shared__ float tile[16][324];
  __shared__ float wl[576];  // [4][16][9]
  int b = blockIdx.y, c0 = blockIdx.z * 16;
  int tx = threadIdx.x & 15, ty = threadIdx.x >> 4;
  int tx0 = (blockIdx.x & 3) << 4, ty0 = (blockIdx.x >> 2) << 4;
  for (int i = threadIdx.x; i < 16 * 324; i += 256) {
    int ci = i / 324, rem = i % 324;
    int r = rem / 18, cc = rem % 18;
    int gy = ty0 + r - 1, gx = tx0 + cc - 1;
    float v = 0.f;
    if (gy >= 0 && gy < 64 && gx >= 0 && gx < 64)
      v = feat[((b * 320 + c0 + ci) * 64 + gy) * 64 + gx];
    tile[ci][rem] = v;
  }
  for (int i = threadIdx.x; i < 576; i += 256) {
    int o = i / 144, rem = i % 144;
    int cl = rem / 9, t = rem % 9;
    wl[i] = w[o * 2880 + (c0 + cl) * 9 + t];
  }
  __syncthreads();
  float acc[4] = {0.f, 0.f, 0.f, 0.f};
  for (int ci = 0; ci < 16; ++ci) {
    #pragma unroll
    for (int kh = 0; kh < 3; ++kh)
      #pragma unroll
      for (int kw = 0; kw < 3; ++kw) {
        float v = tile[ci][(ty + kh) * 18 + tx + kw];
        #pragma unroll
        for (int o = 0; o < 4; ++o)
          acc[o] = fmaf(v, wl[o * 144 + ci * 9 + kh * 3 + kw], acc[o]);
      }
  }
  int y = ty0 + ty, x = tx0 + tx;
  #pragma unroll
  for (int o = 0; o < 4; ++o)
    atomicAdd(&out[((b * 4 + o) * 64 + y) * 64 + x], acc[o]);
}

// ---------------- r1: 1x1 conv 320->9 (raw accumulate; bias+relu folded later) ----
__global__ __launch_bounds__(256) void k_r1(const float* __restrict__ feat,
                                            const float* __restrict__ w,
                                            float* __restrict__ out) {
  __shared__ float wl[576];  // [9][64]
  int c0 = blockIdx.y * 64;
  for (int i = threadIdx.x; i < 576; i += 256) {
    int k = i / 64, cl = i % 64;
    wl[i] = w[k * 320 + c0 + cl];
  }
  __syncthreads();
  int pix = blockIdx.x * 256 + threadIdx.x;  // 16384
  int b = pix >> 12, hw = pix & 4095;
  float acc[9] = {};
  const float* fp = feat + ((size_t)(b * 320 + c0)) * 4096 + hw;
  for (int c = 0; c < 64; ++c) {
    float v = fp[c * 4096];
    #pragma unroll
    for (int k = 0; k < 9; ++k) acc[k] = fmaf(v, wl[k * 64 + c], acc[k]);
  }
  float* op = out + (size_t)(b * 9) * 4096 + hw;
  #pragma unroll
  for (int k = 0; k < 9; ++k) atomicAdd(&op[k * 4096], acc[k]);
}

// ---------------- 3x3 conv 9->9 + ReLU, pad 1 (optional input bias+relu fold) ----
__global__ __launch_bounds__(256) void k_conv9(const float* __restrict__ in,
                                               const float* __restrict__ w9,
                                               const float* __restrict__ bias,
                                               float* __restrict__ out, int H,
                                               const float* __restrict__ prebias) {
  __shared__ float tile[9][324];
  __shared__ float wl[729];
  __shared__ float bl[9];
  __shared__ float pbl[9];
  int b = blockIdx.y;
  int tilesx = H >> 4;
  int tx0 = (blockIdx.x % tilesx) << 4, ty0 = (blockIdx.x / tilesx) << 4;
  int tx = threadIdx.x & 15, ty = threadIdx.x >> 4;
  for (int i = threadIdx.x; i < 729; i += 256) wl[i] = w9[i];
  if (threadIdx.x < 9) {
    bl[threadIdx.x] = bias[threadIdx.x];
    pbl[threadIdx.x] = prebias ? prebias[threadIdx.x] : 0.f;
  }
  __syncthreads();
  for (int i = threadIdx.x; i < 9 * 324; i += 256) {
    int ci = i / 324, rem = i % 324;
    int r = rem / 18, cc = rem % 18;
    int gy = ty0 + r - 1, gx = tx0 + cc - 1;
    float v = 0.f;
    if (gy >= 0 && gy < H && gx >= 0 && gx < H) {
      v = in[((size_t)(b * 9 + ci) * H + gy) * H + gx];
      if (prebias) v = fmaxf(v + pbl[ci], 0.f);
    }
    tile[ci][rem] = v;
  }
  __syncthreads();
  float acc[9] = {};
  for (int ci = 0; ci < 9; ++ci) {
    #pragma unroll
    for (int kh = 0; kh < 3; ++kh)
      #pragma unroll
      for (int kw = 0; kw < 3; ++kw) {
        float v = tile[ci][(ty + kh) * 18 + tx + kw];
        #pragma unroll
        for (int k = 0; k < 9; ++k)
          acc[k] = fmaf(v, wl[(k * 9 + ci) * 9 + kh * 3 + kw], acc[k]);
      }
  }
  int y = ty0 + ty, x = tx0 + tx;
  #pragma unroll
  for (int k = 0; k < 9; ++k)
    out[((size_t)(b * 9 + k) * H + y) * H + x] = fmaxf(acc[k] + bl[k], 0.f);
}

// ---------------- transposed conv 9->9, k=4, s=2, p=1 ----------------
__global__ __launch_bounds__(256) void k_convt9(const float* __restrict__ in,
                                                const float* __restrict__ wt,
                                                const float* __restrict__ bias,
                                                float* __restrict__ out, int Hin) {
  __shared__ float tile[9][100];
  __shared__ float wl[1296];
  __shared__ float bl[9];
  int b = blockIdx.y;
  int Hout = Hin * 2;
  int tilesx = Hout >> 4;
  int tx0 = (blockIdx.x % tilesx) << 4, ty0 = (blockIdx.x / tilesx) << 4;
  int tx = threadIdx.x & 15, ty = threadIdx.x >> 4;
  int ihb = (ty0 >> 1) - 1, iwb = (tx0 >> 1) - 1;
  for (int i = threadIdx.x; i < 1296; i += 256) wl[i] = wt[i];
  if (threadIdx.x < 9) bl[threadIdx.x] = bias[threadIdx.x];
  for (int i = threadIdx.x; i < 900; i += 256) {
    int ci = i / 100, rem = i % 100;
    int r = rem / 10, cc = rem % 10;
    int gy = ihb + r, gx = iwb + cc;
    float v = 0.f;
    if (gy >= 0 && gy < Hin && gx >= 0 && gx < Hin)
      v = in[((size_t)(b * 9 + ci) * Hin + gy) * Hin + gx];
    tile[ci][rem] = v;
  }
  __syncthreads();
  int oy = ty0 + ty, ox = tx0 + tx;
  int p = oy & 1, q = ox & 1;
  int lr0 = ((oy + p - 2) >> 1) - ihb;
  int lc0 = ((ox + q - 2) >> 1) - iwb;
  float acc[9] = {};
  for (int ci = 0; ci < 9; ++ci) {
    #pragma unroll
    for (int a = 0; a < 2; ++a) {
      int kh = p + 2 * a, lr = lr0 + a;
      #pragma unroll
      for (int e = 0; e < 2; ++e) {
        int kw = q + 2 * e, lc = lc0 + e;
        float v = tile[ci][lr * 10 + lc];
        #pragma unroll
        for (int k = 0; k < 9; ++k)
          acc[k] = fmaf(v, wl[((ci * 9 + k) * 4 + (3 - kh)) * 4 + (3 - kw)], acc[k]);
      }
    }
  }
  #pragma unroll
  for (int k = 0; k < 9; ++k)
    out[((size_t)(b * 9 + k) * Hout + oy) * Hout + ox] = acc[k] + bl[k];
}

// ---------------- fused: softmax + R^2 + tri_sample + einsum ----------------
// grid 1024 x 256 threads, 4 pixels/thread (one per batch). Writes R, lutp,
// and one R^2 partial per block.
__global__ __launch_bounds__(256) void k_softmax_tri(const float* __restrict__ in,
                                                     const float* __restrict__ img,
                                                     const float* __restrict__ luts,
                                                     float* __restrict__ R,
                                                     float* __restrict__ lutp,
                                                     float* __restrict__ p_sq) {
  __shared__ float sm[4];
  int tg = blockIdx.x * 256 + threadIdx.x;  // 262144 threads
  float sq = 0.f;
  for (int b = 0; b < 4; ++b) {
    int hw = tg;
    const float* ip = in + (size_t)(b * 9) * NPIX + hw;
    float v[9];
    float m = -1e30f;
    #pragma unroll
    for (int k = 0; k < 9; ++k) { v[k] = ip[(size_t)k * NPIX]; m = fmaxf(m, v[k]); }
    float s = 0.f;
    #pragma unroll
    for (int k = 0; k < 9; ++k) { v[k] = expf(v[k] - m); s += v[k]; }
    float inv = 1.f / s;
    float* rp = R + (size_t)(b * 9) * NPIX + hw;
    #pragma unroll
    for (int k = 0; k < 9; ++k) {
      v[k] *= inv;
      rp[(size_t)k * NPIX] = v[k];
      sq += v[k] * v[k];
    }
    // tri-sample
    int i0[3], i1[3];
    float f[3];
    #pragma unroll
    for (int c = 0; c < 3; ++c) {
      float x = img[(size_t)(b * 3 + c) * NPIX + hw];
      float pos = (x * 0.5f + 0.5f) * 32.f;
      float fl = floorf(pos);
      int ii = (int)fl;
      ii = min(max(ii, 0), 32);
      i0[c] = ii;
      i1[c] = min(ii + 1, 32);
      f[c] = pos - fl;
    }
    float fr = f[0], fg = f[1], fb = f[2];
    int off[8];
    off[0] = (i0[2] * 33 + i0[1]) * 33 + i0[0];
    off[1] = (i0[2] * 33 + i0[1]) * 33 + i1[0];
    off[2] = (i0[2] * 33 + i1[1]) * 33 + i0[0];
    off[3] = (i0[2] * 33 + i1[1]) * 33 + i1[0];
    off[4] = (i1[2] * 33 + i0[1]) * 33 + i0[0];
    off[5] = (i1[2] * 33 + i0[1]) * 33 + i1[0];
    off[6] = (i1[2] * 33 + i1[1]) * 33 + i0[0];
    off[7] = (i1[2] * 33 + i1[1]) * 33 + i1[0];
    float wt[8];
    wt[0] = (1 - fb) * (1 - fg) * (1 - fr);
    wt[1] = (1 - fb) * (1 - fg) * fr;
    wt[2] = (1 - fb) * fg * (1 - fr);
    wt[3] = (1 - fb) * fg * fr;
    wt[4] = fb * (1 - fg) * (1 - fr);
    wt[5] = fb * (1 - fg) * fr;
    wt[6] = fb * fg * (1 - fr);
    wt[7] = fb * fg * fr;
    float acc[3] = {0.f, 0.f, 0.f};
    for (int k = 0; k < 9; ++k) {
      float rk = v[k];
      #pragma unroll
      for (int c = 0; c < 3; ++c) {
        const float* lp = luts + (size_t)(k * 3 + c) * 35937;
        float sv = 0.f;
        #pragma unroll
        for (int j = 0; j < 8; ++j) sv = fmaf(lp[off[j]], wt[j], sv);
        acc[c] = fmaf(rk, sv, acc[c]);
      }
    }
    #pragma unroll
    for (int c = 0; c < 3; ++c) lutp[(size_t)(b * 3 + c) * NPIX + hw] = acc[c];
  }
  float t = block_sum(sq, sm);
  if (threadIdx.x == 0) p_sq[blockIdx.x] = t;
}

// ---------------- tv_R partials (no atomics) ----------------
__global__ __launch_bounds__(256) void k_tvr(const float* __restrict__ R,
                                             float* __restrict__ p_tvr) {
  __shared__ float sm[4];
  int tg = blockIdx.x * 256 + threadIdx.x;  // 262144 threads, 36 elems each
  float s = 0.f;
  for (int it = 0; it < 36; ++it) {
    size_t e = (size_t)it * 262144 + tg;
    int w = e & 511, h = (e >> 9) & 511;
    float v = R[e];
    if (w < 511) s += fabsf(v - R[e + 1]);
    if (h < 511) s += fabsf(v - R[e + 512]);
  }
  float t = block_sum(s, sm);
  if (threadIdx.x == 0) p_tvr[blockIdx.x] = t;
}

// ---------------- f1: 3->64 3x3 + ReLU (one batch) ----------------
__global__ __launch_bounds__(256) void k_f1(const float* __restrict__ inp,
                                            const float* __restrict__ w,
                                            const float* __restrict__ bias,
                                            float* __restrict__ h, int b) {
  __shared__ float tile[3][324];
  __shared__ float wl[432];
  __shared__ float bl[16];
  int g = blockIdx.y;
  int tx0 = (blockIdx.x & 31) << 4, ty0 = (blockIdx.x >> 5) << 4;
  int tx = threadIdx.x & 15, ty = threadIdx.x >> 4;
  for (int i = threadIdx.x; i < 432; i += 256) wl[i] = w[g * 432 + i];
  if (threadIdx.x < 16) bl[threadIdx.x] = bias[g * 16 + threadIdx.x];
  for (int i = threadIdx.x; i < 3 * 324; i += 256) {
    int ci = i / 324, rem = i % 324;
    int r = rem / 18, cc = rem % 18;
    int gy = ty0 + r - 1, gx = tx0 + cc - 1;
    float v = 0.f;
    if (gy >= 0 && gy < 512 && gx >= 0 && gx < 512)
      v = inp[(size_t)(b * 3 + ci) * NPIX + gy * 512 + gx];
    tile[ci][rem] = v;
  }
  __syncthreads();
  float acc[16] = {};
  for (int ci = 0; ci < 3; ++ci)
    #pragma unroll
    for (int kh = 0; kh < 3; ++kh)
      #pragma unroll
      for (int kw = 0; kw < 3; ++kw) {
        float v = tile[ci][(ty + kh) * 18 + tx + kw];
        #pragma unroll
        for (int o = 0; o < 16; ++o)
          acc[o] = fmaf(v, wl[(o * 3 + ci) * 9 + kh * 3 + kw], acc[o]);
      }
  int y = ty0 + ty, x = tx0 + tx;
  #pragma unroll
  for (int o = 0; o < 16; ++o)
    h[(size_t)(g * 16 + o) * NPIX + y * 512 + x] = fmaxf(acc[o] + bl[o], 0.f);
}

// ---------------- f2: 64->3 3x3 (one batch) ----------------
__global__ __launch_bounds__(256) void k_f2(const float* __restrict__ h,
                                            const float* __restrict__ w,
                                            const float* __restrict__ bias,
                                            float* __restrict__ outp, int b) {
  __shared__ float tile[8][324];
  __shared__ float wl[1728];
  int tx0 = (blockIdx.x & 31) << 4, ty0 = (blockIdx.x >> 5) << 4;
  int tx = threadIdx.x & 15, ty = threadIdx.x >> 4;
  for (int i = threadIdx.x; i < 1728; i += 256) wl[i] = w[i];
  float acc[3] = {0.f, 0.f, 0.f};
  for (int c0 = 0; c0 < 64; c0 += 8) {
    __syncthreads();
    for (int i = threadIdx.x; i < 8 * 324; i += 256) {
      int ci = i / 324, rem = i % 324;
      int r = rem / 18, cc = rem % 18;
      int gy = ty0 + r - 1, gx = tx0 + cc - 1;
      float v = 0.f;
      if (gy >= 0 && gy < 512 && gx >= 0 && gx < 512)
        v = h[(size_t)(c0 + ci) * NPIX + gy * 512 + gx];
      tile[ci][rem] = v;
    }
    __syncthreads();
    for (int ci = 0; ci < 8; ++ci)
      #pragma unroll
      for (int kh = 0; kh < 3; ++kh)
        #pragma unroll
        for (int kw = 0; kw < 3; ++kw) {
          float v = tile[ci][(ty + kh) * 18 + tx + kw];
          #pragma unroll
          for (int o = 0; o < 3; ++o)
            acc[o] = fmaf(v, wl[(o * 64 + c0 + ci) * 9 + kh * 3 + kw], acc[o]);
        }
  }
  int y = ty0 + ty, x = tx0 + tx;
  #pragma unroll
  for (int o = 0; o < 3; ++o)
    outp[(size_t)(b * 3 + o) * NPIX + y * 512 + x] = acc[o] + bias[o];
}

// ---------------- tv3d + mono partials (no atomics) ----------------
__global__ __launch_bounds__(256) void k_tv3d(const float* __restrict__ luts,
                                              float* __restrict__ p_tv,
                                              float* __restrict__ p_mn) {
  __shared__ float sm[4];
  float tv = 0.f, mn = 0.f;
  for (int it = 0; it < 8; ++it) {
    int e = it * 131072 + blockIdx.x * 256 + threadIdx.x;
    if (e < 970299) {
      int rem = e % 35937;
      int ib = rem / 1089, ig = (rem / 33) % 33, ir = rem % 33;
      float v = luts[e];
      if (ir < 32) {
        float d = v - luts[e + 1];
        float wgt = (ir == 0 || ir == 31) ? 2.f : 1.f;
        tv += wgt * d * d;
        mn += fmaxf(d, 0.f);
      }
      if (ig < 32) {
        float d = v - luts[e + 33];
        float wgt = (ig == 0 || ig == 31) ? 2.f : 1.f;
        tv += wgt * d * d;
        mn += fmaxf(d, 0.f);
      }
      if (ib < 32) {
        float d = v - luts[e + 1089];
        float wgt = (ib == 0 || ib == 31) ? 2.f : 1.f;
        tv += wgt * d * d;
        mn += fmaxf(d, 0.f);
      }
    }
  }
  float t1 = block_sum(tv, sm);
  float t2 = block_sum(mn, sm);
  if (threadIdx.x == 0) { p_tv[blockIdx.x] = t1; p_mn[blockIdx.x] = t2; }
}

// ---------------- finalize scalar (sums all partials) ----------------
__global__ __launch_bounds__(256) void k_final(const float* __restrict__ parts,
                                               float* __restrict__ out) {
  __shared__ float sm[4];
  float s_sq = 0.f, s_tvr = 0.f, s_tv = 0.f, s_mn = 0.f;
  for (int i = threadIdx.x; i < 1024; i += 256) s_sq += parts[i];
  for (int i = threadIdx.x; i < 1024; i += 256) s_tvr += parts[1024 + i];
  for (int i = threadIdx.x; i < 512; i += 256) s_tv += parts[2048 + i];
  for (int i = threadIdx.x; i < 512; i += 256) s_mn += parts[2560 + i];
  float t_sq = block_sum(s_sq, sm);
  float t_tvr = block_sum(s_tvr, sm);
  float t_tv = block_sum(s_tv, sm);
  float t_mn = block_sum(s_mn, sm);
  if (threadIdx.x == 0)
    out[0] = 0.001f * (t_sq / 9437184.f + t_tv / 104544.f + t_tvr / 9418752.f) +
             10.f * (t_mn / 104544.f);
}

extern "C" void kernel_launch(void* const* d_in, const int* in_sizes, int n_in,
                              void* d_out, int out_size, void* d_ws, size_t ws_size,
                              hipStream_t stream) {
  const float* feat = (const float*)d_in[0];
  const float* img = (const float*)d_in[1];
  const float* conv_out_w = (const float*)d_in[2];
  const float* conv_out_b = (const float*)d_in[3];
  const float* r1_w = (const float*)d_in[4];
  const float* r1_b = (const float*)d_in[5];
  const float* r2_w = (const float*)d_in[6];
  const float* r2_b = (const float*)d_in[7];
  const float* rt1_w = (const float*)d_in[8];
  const float* rt1_b = (const float*)d_in[9];
  const float* r3_w = (const float*)d_in[10];
  const float* r3_b = (const float*)d_in[11];
  const float* rt2_w = (const float*)d_in[12];
  const float* rt2_b = (const float*)d_in[13];
  const float* r4_w = (const float*)d_in[14];
  const float* r4_b = (const float*)d_in[15];
  const float* rt3_w = (const float*)d_in[16];
  const float* rt3_b = (const float*)d_in[17];
  const float* luts = (const float*)d_in[18];
  const float* f1_w = (const float*)d_in[19];
  const float* f1_b = (const float*)d_in[20];
  const float* f2_w = (const float*)d_in[21];
  const float* f2_b = (const float*)d_in[22];

  float* out_noise = (float*)d_out;       // 65536
  float* out_img = out_noise + 65536;     // 3145728
  float* out_loss = out_img + 3145728;    // 1

  char* ws = (char*)d_ws;
  float* parts = (float*)ws;                                // 3072 floats (16KB pad)
  float* bufA = (float*)(ws + 16384);                       // 37748736 B
  float* bufB = (float*)(ws + 16384 + 37748736);            // 37748736 B
  float* lutp = (float*)(ws + 16384 + 2ll * 37748736);      // 12582912 B
  float* hbuf = bufA;  // 67MB, spans bufA+bufB (raw r and R both dead by then)

  // zero r1 accumulation region (4*9*4096 floats)
  hipMemsetAsync(bufA, 0, 589824 * 4, stream);

  k_init_noise<<<256, 256, 0, stream>>>(conv_out_b, out_noise);
  k_conv_noise<<<dim3(16, 4, 20), 256, 0, stream>>>(feat, conv_out_w, out_noise);
  k_r1<<<dim3(64, 5), 256, 0, stream>>>(feat, r1_w, bufA);
  k_conv9<<<dim3(16, 4), 256, 0, stream>>>(bufA, r2_w, r2_b, bufB, 64, r1_b);
  k_convt9<<<dim3(64, 4), 256, 0, stream>>>(bufB, rt1_w, rt1_b, bufA, 64);
  k_conv9<<<dim3(64, 4), 256, 0, stream>>>(bufA, r3_w, r3_b, bufB, 128, nullptr);
  k_convt9<<<dim3(256, 4), 256, 0, stream>>>(bufB, rt2_w, rt2_b, bufA, 128);
  k_conv9<<<dim3(256, 4), 256, 0, stream>>>(bufA, r4_w, r4_b, bufB, 256, nullptr);
  k_convt9<<<dim3(1024, 4), 256, 0, stream>>>(bufB, rt3_w, rt3_b, bufA, 256);
  k_softmax_tri<<<1024, 256, 0, stream>>>(bufA, img, luts, bufB, lutp, parts);
  k_tvr<<<1024, 256, 0, stream>>>(bufB, parts + 1024);
  for (int b = 0; b < 4; ++b) {
    k_f1<<<dim3(1024, 4), 256, 0, stream>>>(lutp, f1_w, f1_b, hbuf, b);
    k_f2<<<1024, 256, 0, stream>>>(hbuf, f2_w, f2_b, out_img, b);
  }
  k_tv3d<<<512, 256, 0, stream>>>(luts, parts + 2048, parts + 2560);
  k_final<<<1, 256, 0, stream>>>(parts, out_loss);
}

// Round 4
// 750.862 us; speedup vs baseline: 3.2449x; 1.5607x over previous
//
#include <hip/hip_runtime.h>
#include <hip/hip_fp16.h>

#define NPIX 262144  // 512*512

// ---------------- reduction helper ----------------
__device__ inline float block_sum(float v, float* sm) {
  #pragma unroll
  for (int off = 32; off > 0; off >>= 1) v += __shfl_down(v, off, 64);
  int lane = threadIdx.x & 63, wid = threadIdx.x >> 6;
  __syncthreads();
  if (lane == 0) sm[wid] = v;
  __syncthreads();
  float r = 0.f;
  if (threadIdx.x < 4) r = sm[threadIdx.x];
  r += __shfl_down(r, 2, 64);
  r += __shfl_down(r, 1, 64);
  return r;  // thread 0 holds the block total
}

// ---------------- noise_pred: 320->4 3x3 conv, pad 1, 64x64 ----------------
__global__ __launch_bounds__(256) void k_init_noise(const float* __restrict__ bias,
                                                    float* __restrict__ out) {
  int i = blockIdx.x * 256 + threadIdx.x;  // 65536
  int c = (i >> 12) & 3;
  out[i] = bias[c];
}

__global__ __launch_bounds__(256) void k_conv_noise(const float* __restrict__ feat,
                                                    const float* __restrict__ w,
                                                    float* __restrict__ out) {
  __shared__ float tile[16][324];
  __shared__ float wl[576];  // [4][16][9]
  int b = blockIdx.y, c0 = blockIdx.z * 16;
  int tx = threadIdx.x & 15, ty = threadIdx.x >> 4;
  int tx0 = (blockIdx.x & 3) << 4, ty0 = (blockIdx.x >> 2) << 4;
  for (int i = threadIdx.x; i < 16 * 324; i += 256) {
    int ci = i / 324, rem = i % 324;
    int r = rem / 18, cc = rem % 18;
    int gy = ty0 + r - 1, gx = tx0 + cc - 1;
    float v = 0.f;
    if (gy >= 0 && gy < 64 && gx >= 0 && gx < 64)
      v = feat[((b * 320 + c0 + ci) * 64 + gy) * 64 + gx];
    tile[ci][rem] = v;
  }
  for (int i = threadIdx.x; i < 576; i += 256) {
    int o = i / 144, rem = i % 144;
    int cl = rem / 9, t = rem % 9;
    wl[i] = w[o * 2880 + (c0 + cl) * 9 + t];
  }
  __syncthreads();
  float acc[4] = {0.f, 0.f, 0.f, 0.f};
  for (int ci = 0; ci < 16; ++ci) {
    #pragma unroll
    for (int kh = 0; kh < 3; ++kh)
      #pragma unroll
      for (int kw = 0; kw < 3; ++kw) {
        float v = tile[ci][(ty + kh) * 18 + tx + kw];
        #pragma unroll
        for (int o = 0; o < 4; ++o)
          acc[o] = fmaf(v, wl[o * 144 + ci * 9 + kh * 3 + kw], acc[o]);
      }
  }
  int y = ty0 + ty, x = tx0 + tx;
  #pragma unroll
  for (int o = 0; o < 4; ++o)
    atomicAdd(&out[((b * 4 + o) * 64 + y) * 64 + x], acc[o]);
}

// ---------------- r1: 1x1 conv 320->9 (raw accumulate) ----------------
__global__ __launch_bounds__(256) void k_r1(const float* __restrict__ feat,
                                            const float* __restrict__ w,
                                            float* __restrict__ out) {
  __shared__ float wl[576];  // [9][64]
  int c0 = blockIdx.y * 64;
  for (int i = threadIdx.x; i < 576; i += 256) {
    int k = i / 64, cl = i % 64;
    wl[i] = w[k * 320 + c0 + cl];
  }
  __syncthreads();
  int pix = blockIdx.x * 256 + threadIdx.x;  // 16384
  int b = pix >> 12, hw = pix & 4095;
  float acc[9] = {};
  const float* fp = feat + ((size_t)(b * 320 + c0)) * 4096 + hw;
  for (int c = 0; c < 64; ++c) {
    float v = fp[c * 4096];
    #pragma unroll
    for (int k = 0; k < 9; ++k) acc[k] = fmaf(v, wl[k * 64 + c], acc[k]);
  }
  float* op = out + (size_t)(b * 9) * 4096 + hw;
  #pragma unroll
  for (int k = 0; k < 9; ++k) atomicAdd(&op[k * 4096], acc[k]);
}

// ---------------- 3x3 conv 9->9 + ReLU, pad 1 ----------------
__global__ __launch_bounds__(256) void k_conv9(const float* __restrict__ in,
                                               const float* __restrict__ w9,
                                               const float* __restrict__ bias,
                                               float* __restrict__ out, int H,
                                               const float* __restrict__ prebias) {
  __shared__ float tile[9][324];
  __shared__ float wl[729];
  __shared__ float bl[9];
  __shared__ float pbl[9];
  int b = blockIdx.y;
  int tilesx = H >> 4;
  int tx0 = (blockIdx.x % tilesx) << 4, ty0 = (blockIdx.x / tilesx) << 4;
  int tx = threadIdx.x & 15, ty = threadIdx.x >> 4;
  for (int i = threadIdx.x; i < 729; i += 256) wl[i] = w9[i];
  if (threadIdx.x < 9) {
    bl[threadIdx.x] = bias[threadIdx.x];
    pbl[threadIdx.x] = prebias ? prebias[threadIdx.x] : 0.f;
  }
  __syncthreads();
  for (int i = threadIdx.x; i < 9 * 324; i += 256) {
    int ci = i / 324, rem = i % 324;
    int r = rem / 18, cc = rem % 18;
    int gy = ty0 + r - 1, gx = tx0 + cc - 1;
    float v = 0.f;
    if (gy >= 0 && gy < H && gx >= 0 && gx < H) {
      v = in[((size_t)(b * 9 + ci) * H + gy) * H + gx];
      if (prebias) v = fmaxf(v + pbl[ci], 0.f);
    }
    tile[ci][rem] = v;
  }
  __syncthreads();
  float acc[9] = {};
  for (int ci = 0; ci < 9; ++ci) {
    #pragma unroll
    for (int kh = 0; kh < 3; ++kh)
      #pragma unroll
      for (int kw = 0; kw < 3; ++kw) {
        float v = tile[ci][(ty + kh) * 18 + tx + kw];
        #pragma unroll
        for (int k = 0; k < 9; ++k)
          acc[k] = fmaf(v, wl[(k * 9 + ci) * 9 + kh * 3 + kw], acc[k]);
      }
  }
  int y = ty0 + ty, x = tx0 + tx;
  #pragma unroll
  for (int k = 0; k < 9; ++k)
    out[((size_t)(b * 9 + k) * H + y) * H + x] = fmaxf(acc[k] + bl[k], 0.f);
}

// ---------------- transposed conv 9->9, k=4, s=2, p=1 ----------------
__global__ __launch_bounds__(256) void k_convt9(const float* __restrict__ in,
                                                const float* __restrict__ wt,
                                                const float* __restrict__ bias,
                                                float* __restrict__ out, int Hin) {
  __shared__ float tile[9][100];
  __shared__ float wl[1296];
  __shared__ float bl[9];
  int b = blockIdx.y;
  int Hout = Hin * 2;
  int tilesx = Hout >> 4;
  int tx0 = (blockIdx.x % tilesx) << 4, ty0 = (blockIdx.x / tilesx) << 4;
  int tx = threadIdx.x & 15, ty = threadIdx.x >> 4;
  int ihb = (ty0 >> 1) - 1, iwb = (tx0 >> 1) - 1;
  for (int i = threadIdx.x; i < 1296; i += 256) wl[i] = wt[i];
  if (threadIdx.x < 9) bl[threadIdx.x] = bias[threadIdx.x];
  for (int i = threadIdx.x; i < 900; i += 256) {
    int ci = i / 100, rem = i % 100;
    int r = rem / 10, cc = rem % 10;
    int gy = ihb + r, gx = iwb + cc;
    float v = 0.f;
    if (gy >= 0 && gy < Hin && gx >= 0 && gx < Hin)
      v = in[((size_t)(b * 9 + ci) * Hin + gy) * Hin + gx];
    tile[ci][rem] = v;
  }
  __syncthreads();
  int oy = ty0 + ty, ox = tx0 + tx;
  int p = oy & 1, q = ox & 1;
  int lr0 = ((oy + p - 2) >> 1) - ihb;
  int lc0 = ((ox + q - 2) >> 1) - iwb;
  float acc[9] = {};
  for (int ci = 0; ci < 9; ++ci) {
    #pragma unroll
    for (int a = 0; a < 2; ++a) {
      int kh = p + 2 * a, lr = lr0 + a;
      #pragma unroll
      for (int e = 0; e < 2; ++e) {
        int kw = q + 2 * e, lc = lc0 + e;
        float v = tile[ci][lr * 10 + lc];
        #pragma unroll
        for (int k = 0; k < 9; ++k)
          acc[k] = fmaf(v, wl[((ci * 9 + k) * 4 + (3 - kh)) * 4 + (3 - kw)], acc[k]);
      }
    }
  }
  #pragma unroll
  for (int k = 0; k < 9; ++k)
    out[((size_t)(b * 9 + k) * Hout + oy) * Hout + ox] = acc[k] + bl[k];
}

// ---------------- LUT repack: [27][35937] f32 -> [35937][32] fp16 ----------------
__global__ __launch_bounds__(256) void k_lut_pack(const float* __restrict__ luts,
                                                  __half* __restrict__ lut2) {
  int cell = blockIdx.x * 256 + threadIdx.x;
  if (cell >= 35937) return;
  __half* dst = lut2 + (size_t)cell * 32;
  #pragma unroll
  for (int e = 0; e < 27; ++e) dst[e] = __float2half(luts[e * 35937 + cell]);
  #pragma unroll
  for (int e = 27; e < 32; ++e) dst[e] = __float2half(0.f);
}

// ---------------- fused: softmax + R^2 + tri_sample + einsum ----------------
// one (b,hw) per thread; 4096 blocks x 256 threads = 2^20 threads.
__global__ __launch_bounds__(256) void k_softmax_tri(const float* __restrict__ in,
                                                     const float* __restrict__ img,
                                                     const __half* __restrict__ lut2,
                                                     float* __restrict__ R,
                                                     __half* __restrict__ lutp,
                                                     float* __restrict__ p_sq) {
  __shared__ float sm[4];
  int tg = blockIdx.x * 256 + threadIdx.x;  // [0, 1048576)
  int b = tg >> 18, hw = tg & (NPIX - 1);
  const float* ip = in + (size_t)(b * 9) * NPIX + hw;
  float v[9];
  float m = -1e30f;
  #pragma unroll
  for (int k = 0; k < 9; ++k) { v[k] = ip[(size_t)k * NPIX]; m = fmaxf(m, v[k]); }
  float s = 0.f;
  #pragma unroll
  for (int k = 0; k < 9; ++k) { v[k] = expf(v[k] - m); s += v[k]; }
  float inv = 1.f / s;
  float sq = 0.f;
  float* rp = R + (size_t)(b * 9) * NPIX + hw;
  #pragma unroll
  for (int k = 0; k < 9; ++k) {
    v[k] *= inv;
    rp[(size_t)k * NPIX] = v[k];
    sq += v[k] * v[k];
  }
  // tri-sample indices
  int i0[3], i1[3];
  float f[3];
  #pragma unroll
  for (int c = 0; c < 3; ++c) {
    float x = img[(size_t)(b * 3 + c) * NPIX + hw];
    float pos = (x * 0.5f + 0.5f) * 32.f;
    float fl = floorf(pos);
    int ii = (int)fl;
    ii = min(max(ii, 0), 32);
    i0[c] = ii;
    i1[c] = min(ii + 1, 32);
    f[c] = pos - fl;
  }
  float fr = f[0], fg = f[1], fb = f[2];
  int cells[8];
  float wt8[8];
  cells[0] = (i0[2] * 33 + i0[1]) * 33 + i0[0]; wt8[0] = (1 - fb) * (1 - fg) * (1 - fr);
  cells[1] = (i0[2] * 33 + i0[1]) * 33 + i1[0]; wt8[1] = (1 - fb) * (1 - fg) * fr;
  cells[2] = (i0[2] * 33 + i1[1]) * 33 + i0[0]; wt8[2] = (1 - fb) * fg * (1 - fr);
  cells[3] = (i0[2] * 33 + i1[1]) * 33 + i1[0]; wt8[3] = (1 - fb) * fg * fr;
  cells[4] = (i1[2] * 33 + i0[1]) * 33 + i0[0]; wt8[4] = fb * (1 - fg) * (1 - fr);
  cells[5] = (i1[2] * 33 + i0[1]) * 33 + i1[0]; wt8[5] = fb * (1 - fg) * fr;
  cells[6] = (i1[2] * 33 + i1[1]) * 33 + i0[0]; wt8[6] = fb * fg * (1 - fr);
  cells[7] = (i1[2] * 33 + i1[1]) * 33 + i1[0]; wt8[7] = fb * fg * fr;
  float acc[3] = {0.f, 0.f, 0.f};
  #pragma unroll
  for (int j = 0; j < 8; ++j) {
    float w = wt8[j];
    float wr[9];
    #pragma unroll
    for (int k = 0; k < 9; ++k) wr[k] = w * v[k];
    const uint4* p = (const uint4*)(lut2 + (size_t)cells[j] * 32);
    uint4 q0 = p[0], q1 = p[1], q2 = p[2];
    uint2 q3 = *(const uint2*)(p + 3);
    unsigned int u[14] = {q0.x, q0.y, q0.z, q0.w, q1.x, q1.y, q1.z, q1.w,
                          q2.x, q2.y, q2.z, q2.w, q3.x, q3.y};
    #pragma unroll
    for (int jj = 0; jj < 13; ++jj) {
      float2 f2 = __half22float2(*(__half2*)&u[jj]);
      const int e0 = 2 * jj, e1 = 2 * jj + 1;
      acc[e0 % 3] = fmaf(wr[e0 / 3], f2.x, acc[e0 % 3]);
      acc[e1 % 3] = fmaf(wr[e1 / 3], f2.y, acc[e1 % 3]);
    }
    float2 fl2 = __half22float2(*(__half2*)&u[13]);
    acc[2] = fmaf(wr[8], fl2.x, acc[2]);  // element 26: k=8,c=2
  }
  #pragma unroll
  for (int c = 0; c < 3; ++c)
    lutp[(size_t)(b * 3 + c) * NPIX + hw] = __float2half(acc[c]);
  float t = block_sum(sq, sm);
  if (threadIdx.x == 0) p_sq[blockIdx.x] = t;
}

// ---------------- tv_R partials ----------------
__global__ __launch_bounds__(256) void k_tvr(const float* __restrict__ R,
                                             float* __restrict__ p_tvr) {
  __shared__ float sm[4];
  int tg = blockIdx.x * 256 + threadIdx.x;  // 262144 threads, 36 elems each
  float s = 0.f;
  for (int it = 0; it < 36; ++it) {
    size_t e = (size_t)it * 262144 + tg;
    int w = e & 511, h = (e >> 9) & 511;
    float v = R[e];
    if (w < 511) s += fabsf(v - R[e + 1]);
    if (h < 511) s += fabsf(v - R[e + 512]);
  }
  float t = block_sum(s, sm);
  if (threadIdx.x == 0) p_tvr[blockIdx.x] = t;
}

// ---------------- f1: 3->64 3x3 + ReLU (one batch), fp16 in/out ----------------
__global__ __launch_bounds__(256) void k_f1(const __half* __restrict__ inp,
                                            const float* __restrict__ w,
                                            const float* __restrict__ bias,
                                            __half* __restrict__ h, int b) {
  __shared__ float tile[3][324];
  __shared__ float wl[432];
  __shared__ float bl[16];
  int g = blockIdx.y;
  int tx0 = (blockIdx.x & 31) << 4, ty0 = (blockIdx.x >> 5) << 4;
  int tx = threadIdx.x & 15, ty = threadIdx.x >> 4;
  for (int i = threadIdx.x; i < 432; i += 256) wl[i] = w[g * 432 + i];
  if (threadIdx.x < 16) bl[threadIdx.x] = bias[g * 16 + threadIdx.x];
  for (int i = threadIdx.x; i < 3 * 324; i += 256) {
    int ci = i / 324, rem = i % 324;
    int r = rem / 18, cc = rem % 18;
    int gy = ty0 + r - 1, gx = tx0 + cc - 1;
    float v = 0.f;
    if (gy >= 0 && gy < 512 && gx >= 0 && gx < 512)
      v = __half2float(inp[(size_t)(b * 3 + ci) * NPIX + gy * 512 + gx]);
    tile[ci][rem] = v;
  }
  __syncthreads();
  float acc[16] = {};
  for (int ci = 0; ci < 3; ++ci)
    #pragma unroll
    for (int kh = 0; kh < 3; ++kh)
      #pragma unroll
      for (int kw = 0; kw < 3; ++kw) {
        float v = tile[ci][(ty + kh) * 18 + tx + kw];
        #pragma unroll
        for (int o = 0; o < 16; ++o)
          acc[o] = fmaf(v, wl[(o * 3 + ci) * 9 + kh * 3 + kw], acc[o]);
      }
  int y = ty0 + ty, x = tx0 + tx;
  #pragma unroll
  for (int o = 0; o < 16; ++o)
    h[(size_t)(g * 16 + o) * NPIX + y * 512 + x] =
        __float2half(fmaxf(acc[o] + bl[o], 0.f));
}

// ---------------- f2: 64->3 3x3 (one batch), fp16 in ----------------
__global__ __launch_bounds__(256) void k_f2(const __half* __restrict__ h,
                                            const float* __restrict__ w,
                                            const float* __restrict__ bias,
                                            float* __restrict__ outp, int b) {
  __shared__ float tile[8][324];
  __shared__ float wl[1728];
  int tx0 = (blockIdx.x & 31) << 4, ty0 = (blockIdx.x >> 5) << 4;
  int tx = threadIdx.x & 15, ty = threadIdx.x >> 4;
  for (int i = threadIdx.x; i < 1728; i += 256) wl[i] = w[i];
  float acc[3] = {0.f, 0.f, 0.f};
  for (int c0 = 0; c0 < 64; c0 += 8) {
    __syncthreads();
    for (int i = threadIdx.x; i < 8 * 324; i += 256) {
      int ci = i / 324, rem = i % 324;
      int r = rem / 18, cc = rem % 18;
      int gy = ty0 + r - 1, gx = tx0 + cc - 1;
      float v = 0.f;
      if (gy >= 0 && gy < 512 && gx >= 0 && gx < 512)
        v = __half2float(h[(size_t)(c0 + ci) * NPIX + gy * 512 + gx]);
      tile[ci][rem] = v;
    }
    __syncthreads();
    for (int ci = 0; ci < 8; ++ci)
      #pragma unroll
      for (int kh = 0; kh < 3; ++kh)
        #pragma unroll
        for (int kw = 0; kw < 3; ++kw) {
          float v = tile[ci][(ty + kh) * 18 + tx + kw];
          #pragma unroll
          for (int o = 0; o < 3; ++o)
            acc[o] = fmaf(v, wl[(o * 64 + c0 + ci) * 9 + kh * 3 + kw], acc[o]);
        }
  }
  int y = ty0 + ty, x = tx0 + tx;
  #pragma unroll
  for (int o = 0; o < 3; ++o)
    outp[(size_t)(b * 3 + o) * NPIX + y * 512 + x] = acc[o] + bias[o];
}

// ---------------- tv3d + mono partials ----------------
__global__ __launch_bounds__(256) void k_tv3d(const float* __restrict__ luts,
                                              float* __restrict__ p_tv,
                                              float* __restrict__ p_mn) {
  __shared__ float sm[4];
  float tv = 0.f, mn = 0.f;
  for (int it = 0; it < 8; ++it) {
    int e = it * 131072 + blockIdx.x * 256 + threadIdx.x;
    if (e < 970299) {
      int rem = e % 35937;
      int ib = rem / 1089, ig = (rem / 33) % 33, ir = rem % 33;
      float v = luts[e];
      if (ir < 32) {
        float d = v - luts[e + 1];
        float wgt = (ir == 0 || ir == 31) ? 2.f : 1.f;
        tv += wgt * d * d;
        mn += fmaxf(d, 0.f);
      }
      if (ig < 32) {
        float d = v - luts[e + 33];
        float wgt = (ig == 0 || ig == 31) ? 2.f : 1.f;
        tv += wgt * d * d;
        mn += fmaxf(d, 0.f);
      }
      if (ib < 32) {
        float d = v - luts[e + 1089];
        float wgt = (ib == 0 || ib == 31) ? 2.f : 1.f;
        tv += wgt * d * d;
        mn += fmaxf(d, 0.f);
      }
    }
  }
  float t1 = block_sum(tv, sm);
  float t2 = block_sum(mn, sm);
  if (threadIdx.x == 0) { p_tv[blockIdx.x] = t1; p_mn[blockIdx.x] = t2; }
}

// ---------------- finalize scalar ----------------
__global__ __launch_bounds__(256) void k_final(const float* __restrict__ parts,
                                               float* __restrict__ out) {
  __shared__ float sm[4];
  float s_sq = 0.f, s_tvr = 0.f, s_tv = 0.f, s_mn = 0.f;
  for (int i = threadIdx.x; i < 4096; i += 256) s_sq += parts[i];
  for (int i = threadIdx.x; i < 1024; i += 256) s_tvr += parts[4096 + i];
  for (int i = threadIdx.x; i < 512; i += 256) s_tv += parts[5120 + i];
  for (int i = threadIdx.x; i < 512; i += 256) s_mn += parts[5632 + i];
  float t_sq = block_sum(s_sq, sm);
  float t_tvr = block_sum(s_tvr, sm);
  float t_tv = block_sum(s_tv, sm);
  float t_mn = block_sum(s_mn, sm);
  if (threadIdx.x == 0)
    out[0] = 0.001f * (t_sq / 9437184.f + t_tv / 104544.f + t_tvr / 9418752.f) +
             10.f * (t_mn / 104544.f);
}

extern "C" void kernel_launch(void* const* d_in, const int* in_sizes, int n_in,
                              void* d_out, int out_size, void* d_ws, size_t ws_size,
                              hipStream_t stream) {
  const float* feat = (const float*)d_in[0];
  const float* img = (const float*)d_in[1];
  const float* conv_out_w = (const float*)d_in[2];
  const float* conv_out_b = (const float*)d_in[3];
  const float* r1_w = (const float*)d_in[4];
  const float* r1_b = (const float*)d_in[5];
  const float* r2_w = (const float*)d_in[6];
  const float* r2_b = (const float*)d_in[7];
  const float* rt1_w = (const float*)d_in[8];
  const float* rt1_b = (const float*)d_in[9];
  const float* r3_w = (const float*)d_in[10];
  const float* r3_b = (const float*)d_in[11];
  const float* rt2_w = (const float*)d_in[12];
  const float* rt2_b = (const float*)d_in[13];
  const float* r4_w = (const float*)d_in[14];
  const float* r4_b = (const float*)d_in[15];
  const float* rt3_w = (const float*)d_in[16];
  const float* rt3_b = (const float*)d_in[17];
  const float* luts = (const float*)d_in[18];
  const float* f1_w = (const float*)d_in[19];
  const float* f1_b = (const float*)d_in[20];
  const float* f2_w = (const float*)d_in[21];
  const float* f2_b = (const float*)d_in[22];

  float* out_noise = (float*)d_out;       // 65536
  float* out_img = out_noise + 65536;     // 3145728
  float* out_loss = out_img + 3145728;    // 1

  // ---- workspace layout (total 84,170,816 B < proven 88.1 MB) ----
  char* ws = (char*)d_ws;
  float* parts = (float*)ws;                       // 80 KB (6144 floats used)
  __half* lut2 = (__half*)(ws + 81920);            // 2,299,968 B
  float* bufA = (float*)(ws + 2381888);            // 37,748,736 B
  float* bufB = (float*)(ws + 40130624);           // 37,748,736 B
  __half* lutp = (__half*)(ws + 77879360);         // 6,291,456 B
  __half* hbuf = (__half*)bufA;                    // 33,554,432 B, inside dead bufA

  // zero r1 accumulation region (4*9*4096 floats)
  hipMemsetAsync(bufA, 0, 589824 * 4, stream);

  k_lut_pack<<<141, 256, 0, stream>>>(luts, lut2);
  k_init_noise<<<256, 256, 0, stream>>>(conv_out_b, out_noise);
  k_conv_noise<<<dim3(16, 4, 20), 256, 0, stream>>>(feat, conv_out_w, out_noise);
  k_r1<<<dim3(64, 5), 256, 0, stream>>>(feat, r1_w, bufA);
  k_conv9<<<dim3(16, 4), 256, 0, stream>>>(bufA, r2_w, r2_b, bufB, 64, r1_b);
  k_convt9<<<dim3(64, 4), 256, 0, stream>>>(bufB, rt1_w, rt1_b, bufA, 64);
  k_conv9<<<dim3(64, 4), 256, 0, stream>>>(bufA, r3_w, r3_b, bufB, 128, nullptr);
  k_convt9<<<dim3(256, 4), 256, 0, stream>>>(bufB, rt2_w, rt2_b, bufA, 128);
  k_conv9<<<dim3(256, 4), 256, 0, stream>>>(bufA, r4_w, r4_b, bufB, 256, nullptr);
  k_convt9<<<dim3(1024, 4), 256, 0, stream>>>(bufB, rt3_w, rt3_b, bufA, 256);
  k_softmax_tri<<<4096, 256, 0, stream>>>(bufA, img, lut2, bufB, lutp, parts);
  k_tvr<<<1024, 256, 0, stream>>>(bufB, parts + 4096);
  for (int b = 0; b < 4; ++b) {
    k_f1<<<dim3(1024, 4), 256, 0, stream>>>(lutp, f1_w, f1_b, hbuf, b);
    k_f2<<<1024, 256, 0, stream>>>(hbuf, f2_w, f2_b, out_img, b);
  }
  k_tv3d<<<512, 256, 0, stream>>>(luts, parts + 5120, parts + 5632);
  k_final<<<1, 256, 0, stream>>>(parts, out_loss);
}

// Round 7
// 453.613 us; speedup vs baseline: 5.3712x; 1.6553x over previous
//
#include <hip/hip_runtime.h>
#include <hip/hip_fp16.h>
#include <hip/hip_fp8.h>

#define NPIX 262144  // 512*512

#if defined(__has_builtin)
#if __has_builtin(__builtin_amdgcn_cvt_f32_fp8)
#define HAVE_FP8_CVT 1
#endif
#endif

// sel must be a literal constant for the builtin; switch folds after unroll.
__device__ inline float fp8_byte_to_f(unsigned int w, int sel) {
#ifdef HAVE_FP8_CVT
  switch (sel & 3) {
    case 0: return __builtin_amdgcn_cvt_f32_fp8(w, 0);
    case 1: return __builtin_amdgcn_cvt_f32_fp8(w, 1);
    case 2: return __builtin_amdgcn_cvt_f32_fp8(w, 2);
    default: return __builtin_amdgcn_cvt_f32_fp8(w, 3);
  }
#else
  __hip_fp8_e4m3 q;
  q.__x = (unsigned char)((w >> (8 * sel)) & 0xff);
  return (float)q;
#endif
}

// packed fp16 ReLU (ROCm 7.2 header lacks a viable __hmax2 fp16 overload)
__device__ inline __half2 relu2(__half2 a) {
  __half2 r;
  unsigned int z = 0;
  asm volatile("v_pk_max_f16 %0, %1, %2" : "=v"(r) : "v"(a), "v"(z));
  return r;
}

// ---------------- reduction helper ----------------
__device__ inline float block_sum(float v, float* sm) {
  #pragma unroll
  for (int off = 32; off > 0; off >>= 1) v += __shfl_down(v, off, 64);
  int lane = threadIdx.x & 63, wid = threadIdx.x >> 6;
  __syncthreads();
  if (lane == 0) sm[wid] = v;
  __syncthreads();
  float r = 0.f;
  if (threadIdx.x < 4) r = sm[threadIdx.x];
  r += __shfl_down(r, 2, 64);
  r += __shfl_down(r, 1, 64);
  return r;  // thread 0 holds the block total
}

// ---------------- noise_pred: 320->4 3x3 conv, pad 1, 64x64 ----------------
__global__ __launch_bounds__(256) void k_init_noise(const float* __restrict__ bias,
                                                    float* __restrict__ out) {
  int i = blockIdx.x * 256 + threadIdx.x;  // 65536
  int c = (i >> 12) & 3;
  out[i] = bias[c];
}

__global__ __launch_bounds__(256) void k_conv_noise(const float* __restrict__ feat,
                                                    const float* __restrict__ w,
                                                    float* __restrict__ out) {
  __shared__ float tile[16][324];
  __shared__ float wl[576];  // [4][16][9]
  int b = blockIdx.y, c0 = blockIdx.z * 16;
  int tx = threadIdx.x & 15, ty = threadIdx.x >> 4;
  int tx0 = (blockIdx.x & 3) << 4, ty0 = (blockIdx.x >> 2) << 4;
  for (int i = threadIdx.x; i < 16 * 324; i += 256) {
    int ci = i / 324, rem = i % 324;
    int r = rem / 18, cc = rem % 18;
    int gy = ty0 + r - 1, gx = tx0 + cc - 1;
    float v = 0.f;
    if (gy >= 0 && gy < 64 && gx >= 0 && gx < 64)
      v = feat[((b * 320 + c0 + ci) * 64 + gy) * 64 + gx];
    tile[ci][rem] = v;
  }
  for (int i = threadIdx.x; i < 576; i += 256) {
    int o = i / 144, rem = i % 144;
    int cl = rem / 9, t = rem % 9;
    wl[i] = w[o * 2880 + (c0 + cl) * 9 + t];
  }
  __syncthreads();
  float acc[4] = {0.f, 0.f, 0.f, 0.f};
  for (int ci = 0; ci < 16; ++ci) {
    #pragma unroll
    for (int kh = 0; kh < 3; ++kh)
      #pragma unroll
      for (int kw = 0; kw < 3; ++kw) {
        float v = tile[ci][(ty + kh) * 18 + tx + kw];
        #pragma unroll
        for (int o = 0; o < 4; ++o)
          acc[o] = fmaf(v, wl[o * 144 + ci * 9 + kh * 3 + kw], acc[o]);
      }
  }
  int y = ty0 + ty, x = tx0 + tx;
  #pragma unroll
  for (int o = 0; o < 4; ++o)
    atomicAdd(&out[((b * 4 + o) * 64 + y) * 64 + x], acc[o]);
}

// ---------------- r1: 1x1 conv 320->9 (raw accumulate) ----------------
__global__ __launch_bounds__(256) void k_r1(const float* __restrict__ feat,
                                            const float* __restrict__ w,
                                            float* __restrict__ out) {
  __shared__ float wl[576];  // [9][64]
  int c0 = blockIdx.y * 64;
  for (int i = threadIdx.x; i < 576; i += 256) {
    int k = i / 64, cl = i % 64;
    wl[i] = w[k * 320 + c0 + cl];
  }
  __syncthreads();
  int pix = blockIdx.x * 256 + threadIdx.x;  // 16384
  int b = pix >> 12, hw = pix & 4095;
  float acc[9] = {};
  const float* fp = feat + ((size_t)(b * 320 + c0)) * 4096 + hw;
  for (int c = 0; c < 64; ++c) {
    float v = fp[c * 4096];
    #pragma unroll
    for (int k = 0; k < 9; ++k) acc[k] = fmaf(v, wl[k * 64 + c], acc[k]);
  }
  float* op = out + (size_t)(b * 9) * 4096 + hw;
  #pragma unroll
  for (int k = 0; k < 9; ++k) atomicAdd(&op[k * 4096], acc[k]);
}

// ---------------- 3x3 conv 9->9 + ReLU, pad 1 ----------------
__global__ __launch_bounds__(256) void k_conv9(const float* __restrict__ in,
                                               const float* __restrict__ w9,
                                               const float* __restrict__ bias,
                                               float* __restrict__ out, int H,
                                               const float* __restrict__ prebias) {
  __shared__ float tile[9][324];
  __shared__ float wl[729];
  __shared__ float bl[9];
  __shared__ float pbl[9];
  int b = blockIdx.y;
  int tilesx = H >> 4;
  int tx0 = (blockIdx.x % tilesx) << 4, ty0 = (blockIdx.x / tilesx) << 4;
  int tx = threadIdx.x & 15, ty = threadIdx.x >> 4;
  for (int i = threadIdx.x; i < 729; i += 256) wl[i] = w9[i];
  if (threadIdx.x < 9) {
    bl[threadIdx.x] = bias[threadIdx.x];
    pbl[threadIdx.x] = prebias ? prebias[threadIdx.x] : 0.f;
  }
  __syncthreads();
  for (int i = threadIdx.x; i < 9 * 324; i += 256) {
    int ci = i / 324, rem = i % 324;
    int r = rem / 18, cc = rem % 18;
    int gy = ty0 + r - 1, gx = tx0 + cc - 1;
    float v = 0.f;
    if (gy >= 0 && gy < H && gx >= 0 && gx < H) {
      v = in[((size_t)(b * 9 + ci) * H + gy) * H + gx];
      if (prebias) v = fmaxf(v + pbl[ci], 0.f);
    }
    tile[ci][rem] = v;
  }
  __syncthreads();
  float acc[9] = {};
  for (int ci = 0; ci < 9; ++ci) {
    #pragma unroll
    for (int kh = 0; kh < 3; ++kh)
      #pragma unroll
      for (int kw = 0; kw < 3; ++kw) {
        float v = tile[ci][(ty + kh) * 18 + tx + kw];
        #pragma unroll
        for (int k = 0; k < 9; ++k)
          acc[k] = fmaf(v, wl[(k * 9 + ci) * 9 + kh * 3 + kw], acc[k]);
      }
  }
  int y = ty0 + ty, x = tx0 + tx;
  #pragma unroll
  for (int k = 0; k < 9; ++k)
    out[((size_t)(b * 9 + k) * H + y) * H + x] = fmaxf(acc[k] + bl[k], 0.f);
}

// ---------------- transposed conv 9->9, k=4, s=2, p=1 ----------------
__global__ __launch_bounds__(256) void k_convt9(const float* __restrict__ in,
                                                const float* __restrict__ wt,
                                                const float* __restrict__ bias,
                                                float* __restrict__ out, int Hin) {
  __shared__ float tile[9][100];
  __shared__ float wl[1296];
  __shared__ float bl[9];
  int b = blockIdx.y;
  int Hout = Hin * 2;
  int tilesx = Hout >> 4;
  int tx0 = (blockIdx.x % tilesx) << 4, ty0 = (blockIdx.x / tilesx) << 4;
  int tx = threadIdx.x & 15, ty = threadIdx.x >> 4;
  int ihb = (ty0 >> 1) - 1, iwb = (tx0 >> 1) - 1;
  for (int i = threadIdx.x; i < 1296; i += 256) wl[i] = wt[i];
  if (threadIdx.x < 9) bl[threadIdx.x] = bias[threadIdx.x];
  for (int i = threadIdx.x; i < 900; i += 256) {
    int ci = i / 100, rem = i % 100;
    int r = rem / 10, cc = rem % 10;
    int gy = ihb + r, gx = iwb + cc;
    float v = 0.f;
    if (gy >= 0 && gy < Hin && gx >= 0 && gx < Hin)
      v = in[((size_t)(b * 9 + ci) * Hin + gy) * Hin + gx];
    tile[ci][rem] = v;
  }
  __syncthreads();
  int oy = ty0 + ty, ox = tx0 + tx;
  int p = oy & 1, q = ox & 1;
  int lr0 = ((oy + p - 2) >> 1) - ihb;
  int lc0 = ((ox + q - 2) >> 1) - iwb;
  float acc[9] = {};
  for (int ci = 0; ci < 9; ++ci) {
    #pragma unroll
    for (int a = 0; a < 2; ++a) {
      int kh = p + 2 * a, lr = lr0 + a;
      #pragma unroll
      for (int e = 0; e < 2; ++e) {
        int kw = q + 2 * e, lc = lc0 + e;
        float v = tile[ci][lr * 10 + lc];
        #pragma unroll
        for (int k = 0; k < 9; ++k)
          acc[k] = fmaf(v, wl[((ci * 9 + k) * 4 + (3 - kh)) * 4 + (3 - kw)], acc[k]);
      }
    }
  }
  #pragma unroll
  for (int k = 0; k < 9; ++k)
    out[((size_t)(b * 9 + k) * Hout + oy) * Hout + ox] = acc[k] + bl[k];
}

// ---------------- LUT repack: 32B/cell = 3 fp16 (k=0) + 24 fp8 (k=1..8) -----
__global__ __launch_bounds__(256) void k_lut_pack(const float* __restrict__ luts,
                                                  unsigned char* __restrict__ lutpk) {
  int cell = blockIdx.x * 256 + threadIdx.x;
  if (cell >= 35937) return;
  unsigned char out[32];
  #pragma unroll
  for (int c = 0; c < 3; ++c) {
    unsigned short u = __half_as_ushort(__float2half(luts[c * 35937 + cell]));
    out[2 * c] = (unsigned char)(u & 0xff);
    out[2 * c + 1] = (unsigned char)(u >> 8);
  }
  #pragma unroll
  for (int e = 3; e < 27; ++e) {
    __hip_fp8_e4m3 q(luts[e * 35937 + cell]);
    out[6 + (e - 3)] = q.__x;
  }
  out[30] = 0;
  out[31] = 0;
  uint4* dst = (uint4*)(lutpk + (size_t)cell * 32);
  dst[0] = *(const uint4*)(out);
  dst[1] = *(const uint4*)(out + 16);
}

// ---------------- weight repack for fused f1f2 ----------------
// w1r[ii][j] = half2(w1[2j][ii], w1[2j+1][ii])       ii = ci*9+tap, j out-pair
// w2r[tap][o][j] = half2(w2[o][2j][tap], w2[o][2j+1][tap])  j ci-pair
__global__ __launch_bounds__(256) void k_w_pack(const float* __restrict__ w1,
                                                const float* __restrict__ w2,
                                                __half2* __restrict__ w1r,
                                                __half2* __restrict__ w2r) {
  int t = blockIdx.x * 256 + threadIdx.x;
  if (t < 864) {
    int ii = t >> 5, j = t & 31;
    w1r[t] = __floats2half2_rn(w1[(2 * j) * 27 + ii], w1[(2 * j + 1) * 27 + ii]);
  } else if (t < 1728) {
    int i = t - 864;
    int tap = i / 96, rem = i % 96;
    int o = rem >> 5, j = rem & 31;
    w2r[i] = __floats2half2_rn(w2[o * 576 + (2 * j) * 9 + tap],
                               w2[o * 576 + (2 * j + 1) * 9 + tap]);
  }
}

// ---------------- fused: softmax + R^2 + tri_sample + einsum ----------------
// one (b,hw) per thread; 4096 blocks x 256 threads.
__global__ __launch_bounds__(256) void k_softmax_tri(const float* __restrict__ in,
                                                     const float* __restrict__ img,
                                                     const unsigned char* __restrict__ lutpk,
                                                     __half* __restrict__ R,
                                                     __half* __restrict__ lutp,
                                                     float* __restrict__ p_sq) {
  __shared__ float sm[4];
  int tg = blockIdx.x * 256 + threadIdx.x;  // [0, 1048576)
  int b = tg >> 18, hw = tg & (NPIX - 1);
  const float* ip = in + (size_t)(b * 9) * NPIX + hw;
  float v[9];
  float m = -1e30f;
  #pragma unroll
  for (int k = 0; k < 9; ++k) { v[k] = ip[(size_t)k * NPIX]; m = fmaxf(m, v[k]); }
  float s = 0.f;
  #pragma unroll
  for (int k = 0; k < 9; ++k) { v[k] = expf(v[k] - m); s += v[k]; }
  float inv = 1.f / s;
  float sq = 0.f;
  __half* rp = R + (size_t)(b * 9) * NPIX + hw;
  #pragma unroll
  for (int k = 0; k < 9; ++k) {
    v[k] *= inv;
    rp[(size_t)k * NPIX] = __float2half(v[k]);
    sq += v[k] * v[k];
  }
  // tri-sample indices
  int i0[3], i1[3];
  float f[3];
  #pragma unroll
  for (int c = 0; c < 3; ++c) {
    float x = img[(size_t)(b * 3 + c) * NPIX + hw];
    float pos = (x * 0.5f + 0.5f) * 32.f;
    float fl = floorf(pos);
    int ii = (int)fl;
    ii = min(max(ii, 0), 32);
    i0[c] = ii;
    i1[c] = min(ii + 1, 32);
    f[c] = pos - fl;
  }
  float fr = f[0], fg = f[1], fb = f[2];
  int cells[8];
  float wt8[8];
  cells[0] = (i0[2] * 33 + i0[1]) * 33 + i0[0]; wt8[0] = (1 - fb) * (1 - fg) * (1 - fr);
  cells[1] = (i0[2] * 33 + i0[1]) * 33 + i1[0]; wt8[1] = (1 - fb) * (1 - fg) * fr;
  cells[2] = (i0[2] * 33 + i1[1]) * 33 + i0[0]; wt8[2] = (1 - fb) * fg * (1 - fr);
  cells[3] = (i0[2] * 33 + i1[1]) * 33 + i1[0]; wt8[3] = (1 - fb) * fg * fr;
  cells[4] = (i1[2] * 33 + i0[1]) * 33 + i0[0]; wt8[4] = fb * (1 - fg) * (1 - fr);
  cells[5] = (i1[2] * 33 + i0[1]) * 33 + i1[0]; wt8[5] = fb * (1 - fg) * fr;
  cells[6] = (i1[2] * 33 + i1[1]) * 33 + i0[0]; wt8[6] = fb * fg * (1 - fr);
  cells[7] = (i1[2] * 33 + i1[1]) * 33 + i1[0]; wt8[7] = fb * fg * fr;
  float acc[3] = {0.f, 0.f, 0.f};
  #pragma unroll
  for (int j = 0; j < 8; ++j) {
    const uint4* p = (const uint4*)(lutpk + (size_t)cells[j] * 32);
    uint4 q0 = p[0], q1 = p[1];
    float wv[9];
    #pragma unroll
    for (int k = 0; k < 9; ++k) wv[k] = wt8[j] * v[k];
    // k=0 identity, fp16
    acc[0] = fmaf(wv[0], __half2float(__ushort_as_half((unsigned short)(q0.x & 0xffff))), acc[0]);
    acc[1] = fmaf(wv[0], __half2float(__ushort_as_half((unsigned short)(q0.x >> 16))), acc[1]);
    acc[2] = fmaf(wv[0], __half2float(__ushort_as_half((unsigned short)(q0.y & 0xffff))), acc[2]);
    unsigned int wrds[8] = {q0.x, q0.y, q0.z, q0.w, q1.x, q1.y, q1.z, q1.w};
    #pragma unroll
    for (int e = 3; e < 27; ++e) {
      const int byte = 6 + (e - 3);
      float fv = fp8_byte_to_f(wrds[byte >> 2], byte & 3);
      acc[e % 3] = fmaf(wv[e / 3], fv, acc[e % 3]);
    }
  }
  #pragma unroll
  for (int c = 0; c < 3; ++c)
    lutp[(size_t)(b * 3 + c) * NPIX + hw] = __float2half(acc[c]);
  float t = block_sum(sq, sm);
  if (threadIdx.x == 0) p_sq[blockIdx.x] = t;
}

// ---------------- tv_R partials (fp16 R) ----------------
__global__ __launch_bounds__(256) void k_tvr(const __half* __restrict__ R,
                                             float* __restrict__ p_tvr) {
  __shared__ float sm[4];
  int tg = blockIdx.x * 256 + threadIdx.x;  // 262144 threads, 36 elems each
  float s = 0.f;
  for (int it = 0; it < 36; ++it) {
    size_t e = (size_t)it * 262144 + tg;
    int w = e & 511, h = (e >> 9) & 511;
    float v = __half2float(R[e]);
    if (w < 511) s += fabsf(v - __half2float(R[e + 1]));
    if (h < 511) s += fabsf(v - __half2float(R[e + 512]));
  }
  float t = block_sum(s, sm);
  if (threadIdx.x == 0) p_tvr[blockIdx.x] = t;
}

// ---------------- fused f1+f2: 3->64 relu ->3, all in one block tile --------
// grid (1024 tiles, 4 batch), block 256. 16x16 out tile, 18x18 h halo in LDS.
__global__ __launch_bounds__(256) void k_f1f2(const __half* __restrict__ lutp,
                                              const __half2* __restrict__ w1r,
                                              const float* __restrict__ b1,
                                              const __half2* __restrict__ w2r,
                                              const float* __restrict__ b2,
                                              float* __restrict__ outp) {
  __shared__ __half lutp_t[3][20][20];
  __shared__ __half hlds[324][72];  // 144B row stride: 16B aligned, bank stride 36
  int b = blockIdx.y;
  int tx0 = (blockIdx.x & 31) << 4, ty0 = (blockIdx.x >> 5) << 4;
  int t = threadIdx.x;
  // stage lutp tile 20x20x3 (zero-padded outside image)
  for (int i = t; i < 1200; i += 256) {
    int ci = i / 400, rem = i % 400;
    int r = rem / 20, c = rem % 20;
    int gy = ty0 + r - 2, gx = tx0 + c - 2;
    __half v = __ushort_as_half((unsigned short)0);
    if (gy >= 0 && gy < 512 && gx >= 0 && gx < 512)
      v = lutp[(size_t)(b * 3 + ci) * NPIX + gy * 512 + gx];
    lutp_t[ci][r][c] = v;
  }
  __syncthreads();
  const __half2 z2 = __float2half2_rn(0.f);
  // phase A: h for 18x18 halo pixels, 64 ch as 32 half2 (pairs 2j,2j+1)
  for (int hp = t; hp < 324; hp += 256) {
    int hy = hp / 18, hx = hp % 18;
    int gy = ty0 - 1 + hy, gx = tx0 - 1 + hx;
    __half2 acc[32];
    if (gy >= 0 && gy < 512 && gx >= 0 && gx < 512) {
      #pragma unroll
      for (int j = 0; j < 32; ++j)
        acc[j] = __floats2half2_rn(b1[2 * j], b1[2 * j + 1]);
      #pragma unroll
      for (int ci = 0; ci < 3; ++ci)
        #pragma unroll
        for (int kh = 0; kh < 3; ++kh)
          #pragma unroll
          for (int kw = 0; kw < 3; ++kw) {
            __half2 vv = __half2half2(lutp_t[ci][hy + kh][hx + kw]);
            const int ii = ci * 9 + kh * 3 + kw;
            #pragma unroll
            for (int j = 0; j < 32; ++j)
              acc[j] = __hfma2(vv, w1r[ii * 32 + j], acc[j]);
          }
      #pragma unroll
      for (int j = 0; j < 32; ++j) acc[j] = relu2(acc[j]);
    } else {
      #pragma unroll
      for (int j = 0; j < 32; ++j) acc[j] = z2;
    }
    __half2* dst = (__half2*)&hlds[hp][0];
    #pragma unroll
    for (int j = 0; j < 32; ++j) dst[j] = acc[j];
  }
  __syncthreads();
  // phase B: f2 64->3 from LDS h
  int tyl = t >> 4, txl = t & 15;
  __half2 a0 = z2, a1 = z2, a2 = z2;
  #pragma unroll
  for (int kh = 0; kh < 3; ++kh)
    #pragma unroll
    for (int kw = 0; kw < 3; ++kw) {
      const int tap = kh * 3 + kw;
      int hp = (tyl + kh) * 18 + (txl + kw);
      const __half2* hrow = (const __half2*)&hlds[hp][0];
      #pragma unroll
      for (int j = 0; j < 32; ++j) {
        __half2 h2 = hrow[j];
        a0 = __hfma2(h2, w2r[tap * 96 + j], a0);
        a1 = __hfma2(h2, w2r[tap * 96 + 32 + j], a1);
        a2 = __hfma2(h2, w2r[tap * 96 + 64 + j], a2);
      }
    }
  int y = ty0 + tyl, x = tx0 + txl;
  outp[(size_t)(b * 3 + 0) * NPIX + y * 512 + x] = __low2float(a0) + __high2float(a0) + b2[0];
  outp[(size_t)(b * 3 + 1) * NPIX + y * 512 + x] = __low2float(a1) + __high2float(a1) + b2[1];
  outp[(size_t)(b * 3 + 2) * NPIX + y * 512 + x] = __low2float(a2) + __high2float(a2) + b2[2];
}

// ---------------- tv3d + mono partials ----------------
__global__ __launch_bounds__(256) void k_tv3d(const float* __restrict__ luts,
                                              float* __restrict__ p_tv,
                                              float* __restrict__ p_mn) {
  __shared__ float sm[4];
  float tv = 0.f, mn = 0.f;
  for (int it = 0; it < 8; ++it) {
    int e = it * 131072 + blockIdx.x * 256 + threadIdx.x;
    if (e < 970299) {
      int rem = e % 35937;
      int ib = rem / 1089, ig = (rem / 33) % 33, ir = rem % 33;
      float v = luts[e];
      if (ir < 32) {
        float d = v - luts[e + 1];
        float wgt = (ir == 0 || ir == 31) ? 2.f : 1.f;
        tv += wgt * d * d;
        mn += fmaxf(d, 0.f);
      }
      if (ig < 32) {
        float d = v - luts[e + 33];
        float wgt = (ig == 0 || ig == 31) ? 2.f : 1.f;
        tv += wgt * d * d;
        mn += fmaxf(d, 0.f);
      }
      if (ib < 32) {
        float d = v - luts[e + 1089];
        float wgt = (ib == 0 || ib == 31) ? 2.f : 1.f;
        tv += wgt * d * d;
        mn += fmaxf(d, 0.f);
      }
    }
  }
  float t1 = block_sum(tv, sm);
  float t2 = block_sum(mn, sm);
  if (threadIdx.x == 0) { p_tv[blockIdx.x] = t1; p_mn[blockIdx.x] = t2; }
}

// ---------------- finalize scalar ----------------
__global__ __launch_bounds__(256) void k_final(const float* __restrict__ parts,
                                               float* __restrict__ out) {
  __shared__ float sm[4];
  float s_sq = 0.f, s_tvr = 0.f, s_tv = 0.f, s_mn = 0.f;
  for (int i = threadIdx.x; i < 4096; i += 256) s_sq += parts[i];
  for (int i = threadIdx.x; i < 1024; i += 256) s_tvr += parts[4096 + i];
  for (int i = threadIdx.x; i < 512; i += 256) s_tv += parts[5120 + i];
  for (int i = threadIdx.x; i < 512; i += 256) s_mn += parts[5632 + i];
  float t_sq = block_sum(s_sq, sm);
  float t_tvr = block_sum(s_tvr, sm);
  float t_tv = block_sum(s_tv, sm);
  float t_mn = block_sum(s_mn, sm);
  if (threadIdx.x == 0)
    out[0] = 0.001f * (t_sq / 9437184.f + t_tv / 104544.f + t_tvr / 9418752.f) +
             10.f * (t_mn / 104544.f);
}

extern "C" void kernel_launch(void* const* d_in, const int* in_sizes, int n_in,
                              void* d_out, int out_size, void* d_ws, size_t ws_size,
                              hipStream_t stream) {
  const float* feat = (const float*)d_in[0];
  const float* img = (const float*)d_in[1];
  const float* conv_out_w = (const float*)d_in[2];
  const float* conv_out_b = (const float*)d_in[3];
  const float* r1_w = (const float*)d_in[4];
  const float* r1_b = (const float*)d_in[5];
  const float* r2_w = (const float*)d_in[6];
  const float* r2_b = (const float*)d_in[7];
  const float* rt1_w = (const float*)d_in[8];
  const float* rt1_b = (const float*)d_in[9];
  const float* r3_w = (const float*)d_in[10];
  const float* r3_b = (const float*)d_in[11];
  const float* rt2_w = (const float*)d_in[12];
  const float* rt2_b = (const float*)d_in[13];
  const float* r4_w = (const float*)d_in[14];
  const float* r4_b = (const float*)d_in[15];
  const float* rt3_w = (const float*)d_in[16];
  const float* rt3_b = (const float*)d_in[17];
  const float* luts = (const float*)d_in[18];
  const float* f1_w = (const float*)d_in[19];
  const float* f1_b = (const float*)d_in[20];
  const float* f2_w = (const float*)d_in[21];
  const float* f2_b = (const float*)d_in[22];

  float* out_noise = (float*)d_out;       // 65536
  float* out_img = out_noise + 65536;     // 3145728
  float* out_loss = out_img + 3145728;    // 1

  // ---- workspace layout (<= 84,170,816 B, proven capacity) ----
  char* ws = (char*)d_ws;
  float* parts = (float*)ws;                         // 80 KB
  unsigned char* lutpk = (unsigned char*)(ws + 81920);  // 35937*32 = 1,149,984 B
  __half2* w1r = (__half2*)(ws + 1232000);           // 3456 B
  __half2* w2r = (__half2*)(ws + 1235456);           // 3456 B
  float* bufA = (float*)(ws + 2381888);              // 37,748,736 B
  float* bufB = (float*)(ws + 40130624);             // 37,748,736 B (R uses half)
  __half* lutp = (__half*)(ws + 77879360);           // 6,291,456 B
  __half* Rh = (__half*)bufB;

  // zero r1 accumulation region (4*9*4096 floats)
  (void)hipMemsetAsync(bufA, 0, 589824 * 4, stream);

  k_lut_pack<<<141, 256, 0, stream>>>(luts, lutpk);
  k_w_pack<<<7, 256, 0, stream>>>(f1_w, f2_w, w1r, w2r);
  k_init_noise<<<256, 256, 0, stream>>>(conv_out_b, out_noise);
  k_conv_noise<<<dim3(16, 4, 20), 256, 0, stream>>>(feat, conv_out_w, out_noise);
  k_r1<<<dim3(64, 5), 256, 0, stream>>>(feat, r1_w, bufA);
  k_conv9<<<dim3(16, 4), 256, 0, stream>>>(bufA, r2_w, r2_b, bufB, 64, r1_b);
  k_convt9<<<dim3(64, 4), 256, 0, stream>>>(bufB, rt1_w, rt1_b, bufA, 64);
  k_conv9<<<dim3(64, 4), 256, 0, stream>>>(bufA, r3_w, r3_b, bufB, 128, nullptr);
  k_convt9<<<dim3(256, 4), 256, 0, stream>>>(bufB, rt2_w, rt2_b, bufA, 128);
  k_conv9<<<dim3(256, 4), 256, 0, stream>>>(bufA, r4_w, r4_b, bufB, 256, nullptr);
  k_convt9<<<dim3(1024, 4), 256, 0, stream>>>(bufB, rt3_w, rt3_b, bufA, 256);
  k_softmax_tri<<<4096, 256, 0, stream>>>(bufA, img, lutpk, Rh, lutp, parts);
  k_tvr<<<1024, 256, 0, stream>>>(Rh, parts + 4096);
  k_f1f2<<<dim3(1024, 4), 256, 0, stream>>>(lutp, w1r, f1_b, w2r, f2_b, out_img);
  k_tv3d<<<512, 256, 0, stream>>>(luts, parts + 5120, parts + 5632);
  k_final<<<1, 256, 0, stream>>>(parts, out_loss);
}

// Round 9
// 408.945 us; speedup vs baseline: 5.9579x; 1.1092x over previous
//
#include <hip/hip_runtime.h>
#include <hip/hip_fp16.h>
#include <hip/hip_fp8.h>

#define NPIX 262144  // 512*512

#if defined(__has_builtin)
#if __has_builtin(__builtin_amdgcn_cvt_f32_fp8)
#define HAVE_FP8_CVT 1
#endif
#endif

// sel must be a literal constant for the builtin; switch folds after unroll.
__device__ inline float fp8_byte_to_f(unsigned int w, int sel) {
#ifdef HAVE_FP8_CVT
  switch (sel & 3) {
    case 0: return __builtin_amdgcn_cvt_f32_fp8(w, 0);
    case 1: return __builtin_amdgcn_cvt_f32_fp8(w, 1);
    case 2: return __builtin_amdgcn_cvt_f32_fp8(w, 2);
    default: return __builtin_amdgcn_cvt_f32_fp8(w, 3);
  }
#else
  __hip_fp8_e4m3 q;
  q.__x = (unsigned char)((w >> (8 * sel)) & 0xff);
  return (float)q;
#endif
}

typedef __attribute__((ext_vector_type(8))) __fp16 half8;
typedef __attribute__((ext_vector_type(4))) float f32x4;
union FragCvt { uint4 u; half8 h; };

// ---------------- reduction helper ----------------
__device__ inline float block_sum(float v, float* sm) {
  #pragma unroll
  for (int off = 32; off > 0; off >>= 1) v += __shfl_down(v, off, 64);
  int lane = threadIdx.x & 63, wid = threadIdx.x >> 6;
  __syncthreads();
  if (lane == 0) sm[wid] = v;
  __syncthreads();
  float r = 0.f;
  if (threadIdx.x < 4) r = sm[threadIdx.x];
  r += __shfl_down(r, 2, 64);
  r += __shfl_down(r, 1, 64);
  return r;  // thread 0 holds the block total
}

// ---------------- noise_pred: 320->4 3x3 conv, pad 1, 64x64 ----------------
__global__ __launch_bounds__(256) void k_init_noise(const float* __restrict__ bias,
                                                    float* __restrict__ out) {
  int i = blockIdx.x * 256 + threadIdx.x;  // 65536
  int c = (i >> 12) & 3;
  out[i] = bias[c];
}

__global__ __launch_bounds__(256) void k_conv_noise(const float* __restrict__ feat,
                                                    const float* __restrict__ w,
                                                    float* __restrict__ out) {
  __shared__ float tile[16][324];
  __shared__ float wl[576];  // [4][16][9]
  int b = blockIdx.y, c0 = blockIdx.z * 16;
  int tx = threadIdx.x & 15, ty = threadIdx.x >> 4;
  int tx0 = (blockIdx.x & 3) << 4, ty0 = (blockIdx.x >> 2) << 4;
  for (int i = threadIdx.x; i < 16 * 324; i += 256) {
    int ci = i / 324, rem = i % 324;
    int r = rem / 18, cc = rem % 18;
    int gy = ty0 + r - 1, gx = tx0 + cc - 1;
    float v = 0.f;
    if (gy >= 0 && gy < 64 && gx >= 0 && gx < 64)
      v = feat[((b * 320 + c0 + ci) * 64 + gy) * 64 + gx];
    tile[ci][rem] = v;
  }
  for (int i = threadIdx.x; i < 576; i += 256) {
    int o = i / 144, rem = i % 144;
    int cl = rem / 9, t = rem % 9;
    wl[i] = w[o * 2880 + (c0 + cl) * 9 + t];
  }
  __syncthreads();
  float acc[4] = {0.f, 0.f, 0.f, 0.f};
  for (int ci = 0; ci < 16; ++ci) {
    #pragma unroll
    for (int kh = 0; kh < 3; ++kh)
      #pragma unroll
      for (int kw = 0; kw < 3; ++kw) {
        float v = tile[ci][(ty + kh) * 18 + tx + kw];
        #pragma unroll
        for (int o = 0; o < 4; ++o)
          acc[o] = fmaf(v, wl[o * 144 + ci * 9 + kh * 3 + kw], acc[o]);
      }
  }
  int y = ty0 + ty, x = tx0 + tx;
  #pragma unroll
  for (int o = 0; o < 4; ++o)
    atomicAdd(&out[((b * 4 + o) * 64 + y) * 64 + x], acc[o]);
}

// ---------------- r1: 1x1 conv 320->9 (raw accumulate) ----------------
__global__ __launch_bounds__(256) void k_r1(const float* __restrict__ feat,
                                            const float* __restrict__ w,
                                            float* __restrict__ out) {
  __shared__ float wl[576];  // [9][64]
  int c0 = blockIdx.y * 64;
  for (int i = threadIdx.x; i < 576; i += 256) {
    int k = i / 64, cl = i % 64;
    wl[i] = w[k * 320 + c0 + cl];
  }
  __syncthreads();
  int pix = blockIdx.x * 256 + threadIdx.x;  // 16384
  int b = pix >> 12, hw = pix & 4095;
  float acc[9] = {};
  const float* fp = feat + ((size_t)(b * 320 + c0)) * 4096 + hw;
  for (int c = 0; c < 64; ++c) {
    float v = fp[c * 4096];
    #pragma unroll
    for (int k = 0; k < 9; ++k) acc[k] = fmaf(v, wl[k * 64 + c], acc[k]);
  }
  float* op = out + (size_t)(b * 9) * 4096 + hw;
  #pragma unroll
  for (int k = 0; k < 9; ++k) atomicAdd(&op[k * 4096], acc[k]);
}

// ---------------- 3x3 conv 9->9 + ReLU, pad 1 ----------------
__global__ __launch_bounds__(256) void k_conv9(const float* __restrict__ in,
                                               const float* __restrict__ w9,
                                               const float* __restrict__ bias,
                                               float* __restrict__ out, int H,
                                               const float* __restrict__ prebias) {
  __shared__ float tile[9][324];
  __shared__ float wl[729];
  __shared__ float bl[9];
  __shared__ float pbl[9];
  int b = blockIdx.y;
  int tilesx = H >> 4;
  int tx0 = (blockIdx.x % tilesx) << 4, ty0 = (blockIdx.x / tilesx) << 4;
  int tx = threadIdx.x & 15, ty = threadIdx.x >> 4;
  for (int i = threadIdx.x; i < 729; i += 256) wl[i] = w9[i];
  if (threadIdx.x < 9) {
    bl[threadIdx.x] = bias[threadIdx.x];
    pbl[threadIdx.x] = prebias ? prebias[threadIdx.x] : 0.f;
  }
  __syncthreads();
  for (int i = threadIdx.x; i < 9 * 324; i += 256) {
    int ci = i / 324, rem = i % 324;
    int r = rem / 18, cc = rem % 18;
    int gy = ty0 + r - 1, gx = tx0 + cc - 1;
    float v = 0.f;
    if (gy >= 0 && gy < H && gx >= 0 && gx < H) {
      v = in[((size_t)(b * 9 + ci) * H + gy) * H + gx];
      if (prebias) v = fmaxf(v + pbl[ci], 0.f);
    }
    tile[ci][rem] = v;
  }
  __syncthreads();
  float acc[9] = {};
  for (int ci = 0; ci < 9; ++ci) {
    #pragma unroll
    for (int kh = 0; kh < 3; ++kh)
      #pragma unroll
      for (int kw = 0; kw < 3; ++kw) {
        float v = tile[ci][(ty + kh) * 18 + tx + kw];
        #pragma unroll
        for (int k = 0; k < 9; ++k)
          acc[k] = fmaf(v, wl[(k * 9 + ci) * 9 + kh * 3 + kw], acc[k]);
      }
  }
  int y = ty0 + ty, x = tx0 + tx;
  #pragma unroll
  for (int k = 0; k < 9; ++k)
    out[((size_t)(b * 9 + k) * H + y) * H + x] = fmaxf(acc[k] + bl[k], 0.f);
}

// ---------------- transposed conv 9->9, k=4, s=2, p=1 ----------------
__global__ __launch_bounds__(256) void k_convt9(const float* __restrict__ in,
                                                const float* __restrict__ wt,
                                                const float* __restrict__ bias,
                                                float* __restrict__ out, int Hin) {
  __shared__ float tile[9][100];
  __shared__ float wl[1296];
  __shared__ float bl[9];
  int b = blockIdx.y;
  int Hout = Hin * 2;
  int tilesx = Hout >> 4;
  int tx0 = (blockIdx.x % tilesx) << 4, ty0 = (blockIdx.x / tilesx) << 4;
  int tx = threadIdx.x & 15, ty = threadIdx.x >> 4;
  int ihb = (ty0 >> 1) - 1, iwb = (tx0 >> 1) - 1;
  for (int i = threadIdx.x; i < 1296; i += 256) wl[i] = wt[i];
  if (threadIdx.x < 9) bl[threadIdx.x] = bias[threadIdx.x];
  for (int i = threadIdx.x; i < 900; i += 256) {
    int ci = i / 100, rem = i % 100;
    int r = rem / 10, cc = rem % 10;
    int gy = ihb + r, gx = iwb + cc;
    float v = 0.f;
    if (gy >= 0 && gy < Hin && gx >= 0 && gx < Hin)
      v = in[((size_t)(b * 9 + ci) * Hin + gy) * Hin + gx];
    tile[ci][rem] = v;
  }
  __syncthreads();
  int oy = ty0 + ty, ox = tx0 + tx;
  int p = oy & 1, q = ox & 1;
  int lr0 = ((oy + p - 2) >> 1) - ihb;
  int lc0 = ((ox + q - 2) >> 1) - iwb;
  float acc[9] = {};
  for (int ci = 0; ci < 9; ++ci) {
    #pragma unroll
    for (int a = 0; a < 2; ++a) {
      int kh = p + 2 * a, lr = lr0 + a;
      #pragma unroll
      for (int e = 0; e < 2; ++e) {
        int kw = q + 2 * e, lc = lc0 + e;
        float v = tile[ci][lr * 10 + lc];
        #pragma unroll
        for (int k = 0; k < 9; ++k)
          acc[k] = fmaf(v, wl[((ci * 9 + k) * 4 + (3 - kh)) * 4 + (3 - kw)], acc[k]);
      }
    }
  }
  #pragma unroll
  for (int k = 0; k < 9; ++k)
    out[((size_t)(b * 9 + k) * Hout + oy) * Hout + ox] = acc[k] + bl[k];
}

// ---------------- LUT repack: 32B/cell = 3 fp16 (k=0) + 24 fp8 (k=1..8) -----
__global__ __launch_bounds__(256) void k_lut_pack(const float* __restrict__ luts,
                                                  unsigned char* __restrict__ lutpk) {
  int cell = blockIdx.x * 256 + threadIdx.x;
  if (cell >= 35937) return;
  unsigned char out[32];
  #pragma unroll
  for (int c = 0; c < 3; ++c) {
    unsigned short u = __half_as_ushort(__float2half(luts[c * 35937 + cell]));
    out[2 * c] = (unsigned char)(u & 0xff);
    out[2 * c + 1] = (unsigned char)(u >> 8);
  }
  #pragma unroll
  for (int e = 3; e < 27; ++e) {
    __hip_fp8_e4m3 q(luts[e * 35937 + cell]);
    out[6 + (e - 3)] = q.__x;
  }
  out[30] = 0;
  out[31] = 0;
  uint4* dst = (uint4*)(lutpk + (size_t)cell * 32);
  dst[0] = *(const uint4*)(out);
  dst[1] = *(const uint4*)(out + 16);
}

// ---------------- weight repack into MFMA B-fragments ----------------
// 16x16x32 f16 B layout: lane l holds col = l&15, k = (l>>4)*8 + i (i=0..7).
// w1frag[nt][l]: col o = nt*16+(l&15), k = ci*9+tap (27 used, pad 32)
// w2frag[s][l]:  col o = l&15 (3 used), K-step s: tap = s>>1, ch = (s&1)*32 + (l>>4)*8 + i
__global__ __launch_bounds__(256) void k_w_pack(const float* __restrict__ w1,
                                                const float* __restrict__ w2,
                                                uint4* __restrict__ w1frag,
                                                uint4* __restrict__ w2frag) {
  int t = blockIdx.x * 256 + threadIdx.x;
  if (t < 256) {
    int l = t & 63, nt = t >> 6;
    int o = nt * 16 + (l & 15);
    int kb = (l >> 4) * 8;
    unsigned int u[4];
    #pragma unroll
    for (int j = 0; j < 4; ++j) {
      int k0 = kb + 2 * j, k1 = k0 + 1;
      unsigned short h0 = (k0 < 27) ? __half_as_ushort(__float2half(w1[o * 27 + k0])) : 0;
      unsigned short h1 = (k1 < 27) ? __half_as_ushort(__float2half(w1[o * 27 + k1])) : 0;
      u[j] = (unsigned)h0 | ((unsigned)h1 << 16);
    }
    w1frag[t] = make_uint4(u[0], u[1], u[2], u[3]);
  } else if (t < 1408) {
    int i2 = t - 256;
    int s = i2 >> 6, l = i2 & 63;
    int o = l & 15;
    int tap = s >> 1;
    int chb = (s & 1) * 32 + (l >> 4) * 8;
    unsigned int u[4];
    #pragma unroll
    for (int j = 0; j < 4; ++j) {
      int c0 = chb + 2 * j, c1 = c0 + 1;
      unsigned short h0 = (o < 3) ? __half_as_ushort(__float2half(w2[o * 576 + c0 * 9 + tap])) : 0;
      unsigned short h1 = (o < 3) ? __half_as_ushort(__float2half(w2[o * 576 + c1 * 9 + tap])) : 0;
      u[j] = (unsigned)h0 | ((unsigned)h1 << 16);
    }
    w2frag[i2] = make_uint4(u[0], u[1], u[2], u[3]);
  }
}

// ---------------- fused: softmax + R^2 + tri_sample + einsum ----------------
__global__ __launch_bounds__(256) void k_softmax_tri(const float* __restrict__ in,
                                                     const float* __restrict__ img,
                                                     const unsigned char* __restrict__ lutpk,
                                                     __half* __restrict__ R,
                                                     __half* __restrict__ lutp,
                                                     float* __restrict__ p_sq) {
  __shared__ float sm[4];
  int tg = blockIdx.x * 256 + threadIdx.x;  // [0, 1048576)
  int b = tg >> 18, hw = tg & (NPIX - 1);
  const float* ip = in + (size_t)(b * 9) * NPIX + hw;
  float v[9];
  float m = -1e30f;
  #pragma unroll
  for (int k = 0; k < 9; ++k) { v[k] = ip[(size_t)k * NPIX]; m = fmaxf(m, v[k]); }
  float s = 0.f;
  #pragma unroll
  for (int k = 0; k < 9; ++k) { v[k] = expf(v[k] - m); s += v[k]; }
  float inv = 1.f / s;
  float sq = 0.f;
  __half* rp = R + (size_t)(b * 9) * NPIX + hw;
  #pragma unroll
  for (int k = 0; k < 9; ++k) {
    v[k] *= inv;
    rp[(size_t)k * NPIX] = __float2half(v[k]);
    sq += v[k] * v[k];
  }
  int i0[3], i1[3];
  float f[3];
  #pragma unroll
  for (int c = 0; c < 3; ++c) {
    float x = img[(size_t)(b * 3 + c) * NPIX + hw];
    float pos = (x * 0.5f + 0.5f) * 32.f;
    float fl = floorf(pos);
    int ii = (int)fl;
    ii = min(max(ii, 0), 32);
    i0[c] = ii;
    i1[c] = min(ii + 1, 32);
    f[c] = pos - fl;
  }
  float fr = f[0], fg = f[1], fb = f[2];
  int cells[8];
  float wt8[8];
  cells[0] = (i0[2] * 33 + i0[1]) * 33 + i0[0]; wt8[0] = (1 - fb) * (1 - fg) * (1 - fr);
  cells[1] = (i0[2] * 33 + i0[1]) * 33 + i1[0]; wt8[1] = (1 - fb) * (1 - fg) * fr;
  cells[2] = (i0[2] * 33 + i1[1]) * 33 + i0[0]; wt8[2] = (1 - fb) * fg * (1 - fr);
  cells[3] = (i0[2] * 33 + i1[1]) * 33 + i1[0]; wt8[3] = (1 - fb) * fg * fr;
  cells[4] = (i1[2] * 33 + i0[1]) * 33 + i0[0]; wt8[4] = fb * (1 - fg) * (1 - fr);
  cells[5] = (i1[2] * 33 + i0[1]) * 33 + i1[0]; wt8[5] = fb * (1 - fg) * fr;
  cells[6] = (i1[2] * 33 + i1[1]) * 33 + i0[0]; wt8[6] = fb * fg * (1 - fr);
  cells[7] = (i1[2] * 33 + i1[1]) * 33 + i1[0]; wt8[7] = fb * fg * fr;
  float acc[3] = {0.f, 0.f, 0.f};
  #pragma unroll
  for (int j = 0; j < 8; ++j) {
    const uint4* p = (const uint4*)(lutpk + (size_t)cells[j] * 32);
    uint4 q0 = p[0], q1 = p[1];
    float wv[9];
    #pragma unroll
    for (int k = 0; k < 9; ++k) wv[k] = wt8[j] * v[k];
    acc[0] = fmaf(wv[0], __half2float(__ushort_as_half((unsigned short)(q0.x & 0xffff))), acc[0]);
    acc[1] = fmaf(wv[0], __half2float(__ushort_as_half((unsigned short)(q0.x >> 16))), acc[1]);
    acc[2] = fmaf(wv[0], __half2float(__ushort_as_half((unsigned short)(q0.y & 0xffff))), acc[2]);
    unsigned int wrds[8] = {q0.x, q0.y, q0.z, q0.w, q1.x, q1.y, q1.z, q1.w};
    #pragma unroll
    for (int e = 3; e < 27; ++e) {
      const int byte = 6 + (e - 3);
      float fv = fp8_byte_to_f(wrds[byte >> 2], byte & 3);
      acc[e % 3] = fmaf(wv[e / 3], fv, acc[e % 3]);
    }
  }
  #pragma unroll
  for (int c = 0; c < 3; ++c)
    lutp[(size_t)(b * 3 + c) * NPIX + hw] = __float2half(acc[c]);
  float t = block_sum(sq, sm);
  if (threadIdx.x == 0) p_sq[blockIdx.x] = t;
}

// ---------------- tv_R partials (fp16 R) ----------------
__global__ __launch_bounds__(256) void k_tvr(const __half* __restrict__ R,
                                             float* __restrict__ p_tvr) {
  __shared__ float sm[4];
  int tg = blockIdx.x * 256 + threadIdx.x;  // 262144 threads, 36 elems each
  float s = 0.f;
  for (int it = 0; it < 36; ++it) {
    size_t e = (size_t)it * 262144 + tg;
    int w = e & 511, h = (e >> 9) & 511;
    float v = __half2float(R[e]);
    if (w < 511) s += fabsf(v - __half2float(R[e + 1]));
    if (h < 511) s += fabsf(v - __half2float(R[e + 512]));
  }
  float t = block_sum(s, sm);
  if (threadIdx.x == 0) p_tvr[blockIdx.x] = t;
}

// ---------------- fused f1+f2 via MFMA (16x16x32 f16) ----------------
// grid (1024 tiles, 4 batch), block 256 (4 waves). 16x16 out tile, 18x18 halo.
// Phase A: h[324 px][64 ch] = relu(im2col(lutp_t)[324][27] x w1[27][64] + b1), MFMA.
// Phase B: out[256 px][3] = h-im2col[256][576] x w2[576][16pad] + b2, MFMA.
__global__ __launch_bounds__(256) void k_f1f2(const __half* __restrict__ lutp,
                                              const uint4* __restrict__ w1frag,
                                              const float* __restrict__ b1,
                                              const uint4* __restrict__ w2frag,
                                              const float* __restrict__ b2,
                                              float* __restrict__ outp) {
  __shared__ __align__(16) _Float16 lutp_t[1208];  // [3][20][20] + zero slot @1200
  __shared__ __align__(16) _Float16 hlds[324 * 72];  // row stride 72 halves = 144 B
  int b = blockIdx.y;
  int tx0 = (blockIdx.x & 31) << 4, ty0 = (blockIdx.x >> 5) << 4;
  int t = threadIdx.x, lane = t & 63, wid = t >> 6;
  // stage lutp 20x20x3 tile (zero outside image)
  for (int i = t; i < 1200; i += 256) {
    int ci = i / 400, rem = i % 400;
    int r = rem / 20, c = rem % 20;
    int gy = ty0 + r - 2, gx = tx0 + c - 2;
    __half v = __ushort_as_half((unsigned short)0);
    if (gy >= 0 && gy < 512 && gx >= 0 && gx < 512)
      v = lutp[(size_t)(b * 3 + ci) * NPIX + gy * 512 + gx];
    lutp_t[i] = *(const __fp16*)&v;
  }
  if (t < 8) lutp_t[1200 + t] = (_Float16)0.f;
  // per-lane constants
  int kb = (lane >> 4) * 8;
  int off8[8];
  #pragma unroll
  for (int i = 0; i < 8; ++i) {
    int k = kb + i;
    off8[i] = (k < 27) ? ((k / 9) * 400 + ((k % 9) / 3) * 20 + (k % 3)) : -1;
  }
  FragCvt w1f[4];
  #pragma unroll
  for (int nt = 0; nt < 4; ++nt) w1f[nt].u = w1frag[nt * 64 + lane];
  float bias1v[4];
  #pragma unroll
  for (int nt = 0; nt < 4; ++nt) bias1v[nt] = b1[nt * 16 + (lane & 15)];
  bool interior = (tx0 > 0) && (tx0 < 496) && (ty0 > 0) && (ty0 < 496);
  __syncthreads();
  // ---- phase A ----
  for (int mt = wid; mt < 21; mt += 4) {
    int pr = mt * 16 + (lane & 15);
    int pc = min(pr, 323);
    int hy = pc / 18, hx = pc - hy * 18;
    int base = hy * 20 + hx;
    half8 af;
    #pragma unroll
    for (int i = 0; i < 8; ++i) {
      int o_ = off8[i];
      int addr = (o_ < 0) ? 1200 : (base + o_);
      af[i] = lutp_t[addr];
    }
    #pragma unroll
    for (int nt = 0; nt < 4; ++nt) {
      f32x4 c = {bias1v[nt], bias1v[nt], bias1v[nt], bias1v[nt]};
      c = __builtin_amdgcn_mfma_f32_16x16x32_f16(af, w1f[nt].h, c, 0, 0, 0);
      #pragma unroll
      for (int r = 0; r < 4; ++r) {
        int px = mt * 16 + (lane >> 4) * 4 + r;
        if (px < 324) {
          float v = fmaxf(c[r], 0.f);
          if (!interior) {
            int hy2 = px / 18, hx2 = px - hy2 * 18;
            int gy = ty0 - 1 + hy2, gx = tx0 - 1 + hx2;
            if (gy < 0 || gy >= 512 || gx < 0 || gx >= 512) v = 0.f;
          }
          hlds[px * 72 + nt * 16 + (lane & 15)] = (_Float16)v;
        }
      }
    }
  }
  // w2 B-fragments (held in regs across phase B)
  FragCvt w2f[18];
  #pragma unroll
  for (int s = 0; s < 18; ++s) w2f[s].u = w2frag[s * 64 + lane];
  int oc = lane & 15;
  float bias2v = (oc < 3) ? b2[oc] : 0.f;
  __syncthreads();
  // ---- phase B ----
  for (int mt = wid; mt < 16; mt += 4) {
    int p = mt * 16 + (lane & 15);
    int oy = p >> 4, ox = p & 15;
    f32x4 acc = {bias2v, bias2v, bias2v, bias2v};
    #pragma unroll
    for (int s = 0; s < 18; ++s) {
      int tap = s >> 1;
      int hp = (oy + tap / 3) * 18 + ox + tap % 3;
      const half8* ap = (const half8*)(hlds + hp * 72 + (s & 1) * 32 + kb);
      acc = __builtin_amdgcn_mfma_f32_16x16x32_f16(*ap, w2f[s].h, acc, 0, 0, 0);
    }
    if (oc < 3) {
      #pragma unroll
      for (int r = 0; r < 4; ++r) {
        int px = mt * 16 + (lane >> 4) * 4 + r;
        int y = ty0 + (px >> 4), x = tx0 + (px & 15);
        outp[(size_t)(b * 3 + oc) * NPIX + y * 512 + x] = acc[r];
      }
    }
  }
}

// ---------------- tv3d + mono partials ----------------
__global__ __launch_bounds__(256) void k_tv3d(const float* __restrict__ luts,
                                              float* __restrict__ p_tv,
                                              float* __restrict__ p_mn) {
  __shared__ float sm[4];
  float tv = 0.f, mn = 0.f;
  for (int it = 0; it < 8; ++it) {
    int e = it * 131072 + blockIdx.x * 256 + threadIdx.x;
    if (e < 970299) {
      int rem = e % 35937;
      int ib = rem / 1089, ig = (rem / 33) % 33, ir = rem % 33;
      float v = luts[e];
      if (ir < 32) {
        float d = v - luts[e + 1];
        float wgt = (ir == 0 || ir == 31) ? 2.f : 1.f;
        tv += wgt * d * d;
        mn += fmaxf(d, 0.f);
      }
      if (ig < 32) {
        float d = v - luts[e + 33];
        float wgt = (ig == 0 || ig == 31) ? 2.f : 1.f;
        tv += wgt * d * d;
        mn += fmaxf(d, 0.f);
      }
      if (ib < 32) {
        float d = v - luts[e + 1089];
        float wgt = (ib == 0 || ib == 31) ? 2.f : 1.f;
        tv += wgt * d * d;
        mn += fmaxf(d, 0.f);
      }
    }
  }
  float t1 = block_sum(tv, sm);
  float t2 = block_sum(mn, sm);
  if (threadIdx.x == 0) { p_tv[blockIdx.x] = t1; p_mn[blockIdx.x] = t2; }
}

// ---------------- finalize scalar ----------------
__global__ __launch_bounds__(256) void k_final(const float* __restrict__ parts,
                                               float* __restrict__ out) {
  __shared__ float sm[4];
  float s_sq = 0.f, s_tvr = 0.f, s_tv = 0.f, s_mn = 0.f;
  for (int i = threadIdx.x; i < 4096; i += 256) s_sq += parts[i];
  for (int i = threadIdx.x; i < 1024; i += 256) s_tvr += parts[4096 + i];
  for (int i = threadIdx.x; i < 512; i += 256) s_tv += parts[5120 + i];
  for (int i = threadIdx.x; i < 512; i += 256) s_mn += parts[5632 + i];
  float t_sq = block_sum(s_sq, sm);
  float t_tvr = block_sum(s_tvr, sm);
  float t_tv = block_sum(s_tv, sm);
  float t_mn = block_sum(s_mn, sm);
  if (threadIdx.x == 0)
    out[0] = 0.001f * (t_sq / 9437184.f + t_tv / 104544.f + t_tvr / 9418752.f) +
             10.f * (t_mn / 104544.f);
}

extern "C" void kernel_launch(void* const* d_in, const int* in_sizes, int n_in,
                              void* d_out, int out_size, void* d_ws, size_t ws_size,
                              hipStream_t stream) {
  const float* feat = (const float*)d_in[0];
  const float* img = (const float*)d_in[1];
  const float* conv_out_w = (const float*)d_in[2];
  const float* conv_out_b = (const float*)d_in[3];
  const float* r1_w = (const float*)d_in[4];
  const float* r1_b = (const float*)d_in[5];
  const float* r2_w = (const float*)d_in[6];
  const float* r2_b = (const float*)d_in[7];
  const float* rt1_w = (const float*)d_in[8];
  const float* rt1_b = (const float*)d_in[9];
  const float* r3_w = (const float*)d_in[10];
  const float* r3_b = (const float*)d_in[11];
  const float* rt2_w = (const float*)d_in[12];
  const float* rt2_b = (const float*)d_in[13];
  const float* r4_w = (const float*)d_in[14];
  const float* r4_b = (const float*)d_in[15];
  const float* rt3_w = (const float*)d_in[16];
  const float* rt3_b = (const float*)d_in[17];
  const float* luts = (const float*)d_in[18];
  const float* f1_w = (const float*)d_in[19];
  const float* f1_b = (const float*)d_in[20];
  const float* f2_w = (const float*)d_in[21];
  const float* f2_b = (const float*)d_in[22];

  float* out_noise = (float*)d_out;       // 65536
  float* out_img = out_noise + 65536;     // 3145728
  float* out_loss = out_img + 3145728;    // 1

  // ---- workspace layout (<= 84,170,816 B, proven capacity) ----
  char* ws = (char*)d_ws;
  float* parts = (float*)ws;                            // 80 KB
  unsigned char* lutpk = (unsigned char*)(ws + 81920);  // 35937*32 = 1,149,984 B
  uint4* w1frag = (uint4*)(ws + 1232000);               // 4,096 B
  uint4* w2frag = (uint4*)(ws + 1236096);               // 18,432 B
  float* bufA = (float*)(ws + 2381888);                 // 37,748,736 B
  float* bufB = (float*)(ws + 40130624);                // 37,748,736 B (R uses half)
  __half* lutp = (__half*)(ws + 77879360);              // 6,291,456 B
  __half* Rh = (__half*)bufB;

  // zero r1 accumulation region (4*9*4096 floats)
  (void)hipMemsetAsync(bufA, 0, 589824 * 4, stream);

  k_lut_pack<<<141, 256, 0, stream>>>(luts, lutpk);
  k_w_pack<<<6, 256, 0, stream>>>(f1_w, f2_w, w1frag, w2frag);
  k_init_noise<<<256, 256, 0, stream>>>(conv_out_b, out_noise);
  k_conv_noise<<<dim3(16, 4, 20), 256, 0, stream>>>(feat, conv_out_w, out_noise);
  k_r1<<<dim3(64, 5), 256, 0, stream>>>(feat, r1_w, bufA);
  k_conv9<<<dim3(16, 4), 256, 0, stream>>>(bufA, r2_w, r2_b, bufB, 64, r1_b);
  k_convt9<<<dim3(64, 4), 256, 0, stream>>>(bufB, rt1_w, rt1_b, bufA, 64);
  k_conv9<<<dim3(64, 4), 256, 0, stream>>>(bufA, r3_w, r3_b, bufB, 128, nullptr);
  k_convt9<<<dim3(256, 4), 256, 0, stream>>>(bufB, rt2_w, rt2_b, bufA, 128);
  k_conv9<<<dim3(256, 4), 256, 0, stream>>>(bufA, r4_w, r4_b, bufB, 256, nullptr);
  k_convt9<<<dim3(1024, 4), 256, 0, stream>>>(bufB, rt3_w, rt3_b, bufA, 256);
  k_softmax_tri<<<4096, 256, 0, stream>>>(bufA, img, lutpk, Rh, lutp, parts);
  k_tvr<<<1024, 256, 0, stream>>>(Rh, parts + 4096);
  k_f1f2<<<dim3(1024, 4), 256, 0, stream>>>(lutp, w1frag, f1_b, w2frag, f2_b, out_img);
  k_tv3d<<<512, 256, 0, stream>>>(luts, parts + 5120, parts + 5632);
  k_final<<<1, 256, 0, stream>>>(parts, out_loss);
}